// Round 1
// baseline (706.588 us; speedup 1.0000x reference)
//
#include <hip/hip_runtime.h>
#include <hip/hip_bf16.h>

// Problem constants (from reference setup_inputs)
#define NN      10000
#define NE      150000
#define NG      64
#define DIN     128
#define DHID    512
#define DOUT    128

// ---------------------------------------------------------------------------
// Degree / normalization
// ---------------------------------------------------------------------------
__global__ void k_init_deg(float* deg, int n) {
    int i = blockIdx.x * blockDim.x + threadIdx.x;
    if (i < n) deg[i] = 1.0f;  // self-loop
}

__global__ void k_edges_count(const int* __restrict__ dst, float* __restrict__ deg,
                              int* __restrict__ cnt, int E) {
    int e = blockIdx.x * blockDim.x + threadIdx.x;
    if (e < E) {
        int d = dst[e];
        atomicAdd(&deg[d], 1.0f);
        atomicAdd(&cnt[d], 1);
    }
}

__global__ void k_dinv(float* deg, int n) {  // in-place deg -> deg^{-1/2}
    int i = blockIdx.x * blockDim.x + threadIdx.x;
    if (i < n) deg[i] = rsqrtf(deg[i]);
}

// Single-wave exclusive scan over cnt[0..n) -> rp[0..n]
__global__ void k_scan(const int* __restrict__ cnt, int* __restrict__ rp, int n) {
    const int lane = threadIdx.x;  // 64 threads
    int carry = 0;
    for (int base = 0; base < n; base += 64) {
        int i = base + lane;
        int v = (i < n) ? cnt[i] : 0;
        int s = v;
#pragma unroll
        for (int off = 1; off < 64; off <<= 1) {
            int t = __shfl_up(s, off);
            if (lane >= off) s += t;
        }
        if (i < n) rp[i] = carry + s - v;  // exclusive
        carry += __shfl(s, 63);
    }
    if (lane == 0) rp[n] = carry;
}

__global__ void k_scatter(const int* __restrict__ src, const int* __restrict__ dst,
                          const float* __restrict__ dinv, const int* __restrict__ rp,
                          int* __restrict__ fill, int* __restrict__ es,
                          float* __restrict__ ew, int E) {
    int e = blockIdx.x * blockDim.x + threadIdx.x;
    if (e < E) {
        int d = dst[e], s = src[e];
        int p = rp[d] + atomicAdd(&fill[d], 1);
        es[p] = s;
        ew[p] = dinv[s] * dinv[d];
    }
}

// ---------------------------------------------------------------------------
// Aggregation: out[n] = sum_{e: dst=n} hW[src_e]*norm_e + hW[n]*dinv[n]^2 (+bias, relu)
// One block per node; TPB threads each own VEC = M/TPB consecutive features.
// ---------------------------------------------------------------------------
template <int M, int TPB>
__global__ void k_agg(const float* __restrict__ hW, const float* __restrict__ dinv,
                      const int* __restrict__ rp, const int* __restrict__ es,
                      const float* __restrict__ ew, const float* __restrict__ bias,
                      float* __restrict__ out, const int do_relu) {
    constexpr int VEC = M / TPB;
    static_assert(VEC == 2 || VEC == 4, "VEC must be 2 or 4");
    const int node = blockIdx.x;
    const int tid = threadIdx.x;
    __shared__ int s_src[64];
    __shared__ float s_w[64];

    const float di = dinv[node];
    const float sw = di * di;
    float acc[VEC];
    {
        const float* p = hW + (size_t)node * M + tid * VEC;
        if constexpr (VEC == 4) {
            float4 v = *reinterpret_cast<const float4*>(p);
            acc[0] = v.x * sw; acc[1] = v.y * sw; acc[2] = v.z * sw; acc[3] = v.w * sw;
        } else {
            float2 v = *reinterpret_cast<const float2*>(p);
            acc[0] = v.x * sw; acc[1] = v.y * sw;
        }
    }
    const int beg = rp[node], end = rp[node + 1];
    for (int c = beg; c < end; c += 64) {
        const int m = min(64, end - c);
        __syncthreads();
        if (tid < m) { s_src[tid] = es[c + tid]; s_w[tid] = ew[c + tid]; }
        __syncthreads();
        for (int e = 0; e < m; e++) {
            const float w = s_w[e];
            const float* p = hW + (size_t)s_src[e] * M + tid * VEC;
            if constexpr (VEC == 4) {
                float4 v = *reinterpret_cast<const float4*>(p);
                acc[0] = fmaf(v.x, w, acc[0]); acc[1] = fmaf(v.y, w, acc[1]);
                acc[2] = fmaf(v.z, w, acc[2]); acc[3] = fmaf(v.w, w, acc[3]);
            } else {
                float2 v = *reinterpret_cast<const float2*>(p);
                acc[0] = fmaf(v.x, w, acc[0]); acc[1] = fmaf(v.y, w, acc[1]);
            }
        }
    }
#pragma unroll
    for (int v = 0; v < VEC; v++) {
        float r = acc[v] + (bias ? bias[tid * VEC + v] : 0.0f);
        if (do_relu) r = fmaxf(r, 0.0f);
        acc[v] = r;
    }
    float* po = out + (size_t)node * M + tid * VEC;
    if constexpr (VEC == 4) {
        *reinterpret_cast<float4*>(po) = make_float4(acc[0], acc[1], acc[2], acc[3]);
    } else {
        *reinterpret_cast<float2*>(po) = make_float2(acc[0], acc[1]);
    }
}

// ---------------------------------------------------------------------------
// FP32 tiled GEMM: C[N,M] = A[N,K] @ W[K,M]  (+bias, relu if EPI)
// 64x64 tile, BK=16, 256 threads, 4x4 microtile.
// ---------------------------------------------------------------------------
template <bool EPI>
__global__ __launch_bounds__(256) void k_gemm(const float* __restrict__ A,
                                              const float* __restrict__ W,
                                              const float* __restrict__ bias,
                                              float* __restrict__ C,
                                              const int N, const int K, const int M) {
    __shared__ float As[16][64];  // [k][row]
    __shared__ float Bs[16][64];  // [k][col]
    const int tid = threadIdx.x;
    const int col0 = blockIdx.x * 64;
    const int row0 = blockIdx.y * 64;
    const int tx = tid & 15, ty = tid >> 4;
    const int arow = tid >> 2;        // 0..63
    const int acg = (tid & 3) * 4;    // k offset group
    const int brow = tid >> 4;        // 0..15
    const int bcol = (tid & 15) * 4;  // 0..60

    float acc[4][4] = {};
    for (int k0 = 0; k0 < K; k0 += 16) {
        float4 av = make_float4(0.f, 0.f, 0.f, 0.f);
        const int gr = row0 + arow;
        if (gr < N) av = *reinterpret_cast<const float4*>(A + (size_t)gr * K + k0 + acg);
        const float4 bv =
            *reinterpret_cast<const float4*>(W + (size_t)(k0 + brow) * M + col0 + bcol);
        __syncthreads();
        As[acg + 0][arow] = av.x; As[acg + 1][arow] = av.y;
        As[acg + 2][arow] = av.z; As[acg + 3][arow] = av.w;
        *reinterpret_cast<float4*>(&Bs[brow][bcol]) = bv;
        __syncthreads();
#pragma unroll
        for (int kk = 0; kk < 16; kk++) {
            float4 a4 = *reinterpret_cast<const float4*>(&As[kk][ty * 4]);
            float4 b4 = *reinterpret_cast<const float4*>(&Bs[kk][tx * 4]);
            float ar[4] = {a4.x, a4.y, a4.z, a4.w};
            float br[4] = {b4.x, b4.y, b4.z, b4.w};
#pragma unroll
            for (int i = 0; i < 4; i++)
#pragma unroll
                for (int j = 0; j < 4; j++) acc[i][j] = fmaf(ar[i], br[j], acc[i][j]);
        }
    }
#pragma unroll
    for (int i = 0; i < 4; i++) {
        const int r = row0 + ty * 4 + i;
        if (r < N) {
            float4 o;
            if constexpr (EPI) {
                const int cb = col0 + tx * 4;
                o.x = fmaxf(acc[i][0] + bias[cb + 0], 0.f);
                o.y = fmaxf(acc[i][1] + bias[cb + 1], 0.f);
                o.z = fmaxf(acc[i][2] + bias[cb + 2], 0.f);
                o.w = fmaxf(acc[i][3] + bias[cb + 3], 0.f);
            } else {
                o = make_float4(acc[i][0], acc[i][1], acc[i][2], acc[i][3]);
            }
            *reinterpret_cast<float4*>(C + (size_t)r * M + col0 + tx * 4) = o;
        }
    }
}

// ---------------------------------------------------------------------------
// Mean pool over graph ids
// ---------------------------------------------------------------------------
__global__ void k_pool(const float* __restrict__ h, const int* __restrict__ batch,
                       float* __restrict__ out, float* __restrict__ pcnt) {
    const int node = blockIdx.x;
    const int f = threadIdx.x;  // 128
    const int g = batch[node];
    atomicAdd(&out[(size_t)g * DOUT + f], h[(size_t)node * DOUT + f]);
    if (f == 0) atomicAdd(&pcnt[g], 1.0f);
}

__global__ void k_pool_div(float* __restrict__ out, const float* __restrict__ pcnt) {
    const int g = blockIdx.x;
    const int f = threadIdx.x;
    out[(size_t)g * DOUT + f] /= fmaxf(pcnt[g], 1.0f);
}

// ---------------------------------------------------------------------------
extern "C" void kernel_launch(void* const* d_in, const int* in_sizes, int n_in,
                              void* d_out, int out_size, void* d_ws, size_t ws_size,
                              hipStream_t stream) {
    const float* x = (const float*)d_in[0];
    const int* ei = (const int*)d_in[1];
    const int* batch = (const int*)d_in[2];
    const float* W1 = (const float*)d_in[3];  const float* b1 = (const float*)d_in[4];
    const float* W2 = (const float*)d_in[5];  const float* b2 = (const float*)d_in[6];
    const float* W3 = (const float*)d_in[7];  const float* b3 = (const float*)d_in[8];
    const float* W4 = (const float*)d_in[9];  const float* b4 = (const float*)d_in[10];
    const float* W5 = (const float*)d_in[11]; const float* b5 = (const float*)d_in[12];
    const int* src = ei;
    const int* dst = ei + NE;

    // Workspace carve-up (256B aligned)
    char* ws = (char*)d_ws;
    size_t off = 0;
    auto alloc = [&](size_t bytes) -> char* {
        char* p = ws + off;
        off = (off + bytes + 255) & ~(size_t)255;
        return p;
    };
    float* dinv = (float*)alloc(NN * 4);        // deg -> dinv in place
    int* cnt    = (int*)alloc(NN * 4);
    int* rp     = (int*)alloc((NN + 1) * 4);
    int* fill   = (int*)alloc(NN * 4);
    int* es     = (int*)alloc(NE * 4);
    float* ewn  = (float*)alloc(NE * 4);
    float* hA   = (float*)alloc((size_t)NN * DHID * 4);
    float* hB   = (float*)alloc((size_t)NN * DHID * 4);
    float* pcnt = (float*)alloc(NG * 4);
    (void)ws_size; (void)n_in; (void)in_sizes;

    hipMemsetAsync(cnt, 0, NN * 4, stream);
    hipMemsetAsync(fill, 0, NN * 4, stream);
    hipMemsetAsync(d_out, 0, (size_t)out_size * 4, stream);
    hipMemsetAsync(pcnt, 0, NG * 4, stream);

    // Degree + CSR build
    k_init_deg<<<(NN + 255) / 256, 256, 0, stream>>>(dinv, NN);
    k_edges_count<<<(NE + 255) / 256, 256, 0, stream>>>(dst, dinv, cnt, NE);
    k_dinv<<<(NN + 255) / 256, 256, 0, stream>>>(dinv, NN);
    k_scan<<<1, 64, 0, stream>>>(cnt, rp, NN);
    k_scatter<<<(NE + 255) / 256, 256, 0, stream>>>(src, dst, dinv, rp, fill, es, ewn, NE);

    const int gy = (NN + 63) / 64;  // 157

    // Layer 1: reorder  h1 = relu((A_hat x) W1 + b1)   (aggregate in 128-dim)
    k_agg<DIN, 64><<<NN, 64, 0, stream>>>(x, dinv, rp, es, ewn, nullptr, hA, 0);
    k_gemm<true><<<dim3(DHID / 64, gy), 256, 0, stream>>>(hA, W1, b1, hB, NN, DIN, DHID);

    // Layers 2-4: hW = h @ W ; h = relu(A_hat hW + b)
    k_gemm<false><<<dim3(DHID / 64, gy), 256, 0, stream>>>(hB, W2, nullptr, hA, NN, DHID, DHID);
    k_agg<DHID, 128><<<NN, 128, 0, stream>>>(hA, dinv, rp, es, ewn, b2, hB, 1);

    k_gemm<false><<<dim3(DHID / 64, gy), 256, 0, stream>>>(hB, W3, nullptr, hA, NN, DHID, DHID);
    k_agg<DHID, 128><<<NN, 128, 0, stream>>>(hA, dinv, rp, es, ewn, b3, hB, 1);

    k_gemm<false><<<dim3(DHID / 64, gy), 256, 0, stream>>>(hB, W4, nullptr, hA, NN, DHID, DHID);
    k_agg<DHID, 128><<<NN, 128, 0, stream>>>(hA, dinv, rp, es, ewn, b4, hB, 1);

    // Layer 5: hW = h @ W5 (512->128), then aggregate in 128-dim, bias+relu
    k_gemm<false><<<dim3(DOUT / 64, gy), 256, 0, stream>>>(hB, W5, nullptr, hA, NN, DHID, DOUT);
    k_agg<DOUT, 64><<<NN, 64, 0, stream>>>(hA, dinv, rp, es, ewn, b5, hB, 1);

    // Mean pool
    k_pool<<<NN, DOUT, 0, stream>>>(hB, batch, (float*)d_out, pcnt);
    k_pool_div<<<NG, DOUT, 0, stream>>>((float*)d_out, pcnt);
}

// Round 2
// 500.507 us; speedup vs baseline: 1.4117x; 1.4117x over previous
//
#include <hip/hip_runtime.h>
#include <stdint.h>

#define NN 10000
#define NE 150000
#define NG 64
#define DIN 128
#define DHID 512
#define DOUT 128

typedef float f32x4 __attribute__((ext_vector_type(4)));
typedef short s16x8 __attribute__((ext_vector_type(8)));
typedef unsigned short us4 __attribute__((ext_vector_type(4)));
typedef unsigned short us2 __attribute__((ext_vector_type(2)));
typedef unsigned short ushort_t;

// ---------------------------------------------------------------------------
// bf16 helpers (RNE), own impl to avoid header/API variance
// ---------------------------------------------------------------------------
__device__ __forceinline__ ushort_t f2bf(float f) {
    unsigned u = __float_as_uint(f);
    u += 0x7FFFu + ((u >> 16) & 1u);
    return (ushort_t)(u >> 16);
}
__device__ __forceinline__ float bf2f(ushort_t s) {
    return __uint_as_float(((unsigned)s) << 16);
}

__device__ __forceinline__ void gl_lds16(const void* g, void* l) {
    __builtin_amdgcn_global_load_lds(
        (const __attribute__((address_space(1))) unsigned int*)g,
        (__attribute__((address_space(3))) unsigned int*)l, 16, 0, 0);
}

__device__ __forceinline__ void mfma_bf16(f32x4& d, s16x8 a, s16x8 b) {
    asm("v_mfma_f32_16x16x32_bf16 %0, %1, %2, %0" : "+v"(d) : "v"(a), "v"(b));
}

// ---------------------------------------------------------------------------
// CSR build
// ---------------------------------------------------------------------------
__global__ void k_edges_count(const int* __restrict__ dst, int* __restrict__ cnt, int E) {
    int e = blockIdx.x * blockDim.x + threadIdx.x;
    if (e < E) atomicAdd(&cnt[dst[e]], 1);
}

__global__ void k_dinv(const int* __restrict__ cnt, float* __restrict__ dinv, int n) {
    int i = blockIdx.x * blockDim.x + threadIdx.x;
    if (i < n) dinv[i] = rsqrtf(1.0f + (float)cnt[i]);  // +1 self loop
}

// 1024-thread single-block exclusive scan of cnt[0..NN) -> rp[0..NN]
__global__ void k_scan2(const int* __restrict__ cnt, int* __restrict__ rp) {
    const int C = 10;  // 1024*10 >= 10001
    const int t = threadIdx.x;
    const int lane = t & 63, w = t >> 6;
    const int base = t * C;
    int v[C];
    int s = 0;
#pragma unroll
    for (int j = 0; j < C; j++) {
        int i = base + j;
        v[j] = (i < NN) ? cnt[i] : 0;
        s += v[j];
    }
    int sc = s;
#pragma unroll
    for (int off = 1; off < 64; off <<= 1) {
        int tv = __shfl_up(sc, off);
        if (lane >= off) sc += tv;
    }
    __shared__ int wsum[16], woff[16];
    if (lane == 63) wsum[w] = sc;
    __syncthreads();
    if (t == 0) {
        int c = 0;
#pragma unroll
        for (int k = 0; k < 16; k++) { woff[k] = c; c += wsum[k]; }
    }
    __syncthreads();
    int pre = woff[w] + (sc - s);  // exclusive prefix for this thread's chunk
#pragma unroll
    for (int j = 0; j < C; j++) {
        int i = base + j;
        if (i <= NN) rp[i] = pre;
        pre += v[j];
    }
}

__global__ void k_scatter(const int* __restrict__ src, const int* __restrict__ dst,
                          const float* __restrict__ dinv, const int* __restrict__ rp,
                          int* __restrict__ fill, int* __restrict__ es,
                          float* __restrict__ ew, int E) {
    int e = blockIdx.x * blockDim.x + threadIdx.x;
    if (e < E) {
        int d = dst[e], s = src[e];
        int p = rp[d] + atomicAdd(&fill[d], 1);
        es[p] = s;
        ew[p] = dinv[s] * dinv[d];
    }
}

// ---------------------------------------------------------------------------
// Weight transpose + bf16 hi/lo split: W[K][Mw] fp32 -> Wt_h/Wt_l [Mw][K]
// All 5 layers fused in one launch.
// ---------------------------------------------------------------------------
__global__ void k_split_w(const float* __restrict__ W1, const float* __restrict__ W2,
                          const float* __restrict__ W3, const float* __restrict__ W4,
                          const float* __restrict__ W5,
                          ushort_t* __restrict__ th, ushort_t* __restrict__ tl) {
    int t = blockIdx.x * blockDim.x + threadIdx.x;
    const float* W;
    int K, Mw, off, r;
    if (t < 65536)       { W = W1; K = 128; Mw = 512; off = 0;      r = t; }
    else if (t < 327680) { W = W2; K = 512; Mw = 512; off = 65536;  r = t - 65536; }
    else if (t < 589824) { W = W3; K = 512; Mw = 512; off = 327680; r = t - 327680; }
    else if (t < 851968) { W = W4; K = 512; Mw = 512; off = 589824; r = t - 589824; }
    else if (t < 917504) { W = W5; K = 512; Mw = 128; off = 851968; r = t - 851968; }
    else return;
    const int k = r / Mw, m = r % Mw;
    const float f = W[r];  // r = k*Mw + m, coalesced read
    const ushort_t h = f2bf(f);
    const ushort_t l = f2bf(f - bf2f(h));
    const int o = off + m * K + k;
    th[o] = h;
    tl[o] = l;
}

// ---------------------------------------------------------------------------
// bf16x3 split MFMA GEMM: C[M][N] = (Ah+Al)[M][K] @ (Bh+Bl)^T  (Bt is [N][K])
// 128x128 tile, BK=32, 256 threads = 4 waves (2x2 of 64x64), 16x16x32 MFMA.
// EPI: 1 = split-pair out; 2 = bias+relu+split-pair out.
// ---------------------------------------------------------------------------
template <int EPI>
__global__ __launch_bounds__(256, 2) void k_mgemm(
    const ushort_t* __restrict__ Ah, const ushort_t* __restrict__ Al,
    const ushort_t* __restrict__ Bh, const ushort_t* __restrict__ Bl,
    const float* __restrict__ bias,
    ushort_t* __restrict__ Ch, ushort_t* __restrict__ Cl,
    const int M, const int N, const int K) {
    __shared__ ushort_t sAh[128 * 32], sAl[128 * 32], sBh[128 * 32], sBl[128 * 32];
    const int tid = threadIdx.x;
    const int lane = tid & 63, wv = tid >> 6;
    const int ln = lane & 15, lhi = lane >> 4;
    const int kg = lhi * 8;
    const int wr = (wv >> 1) * 64, wc = (wv & 1) * 64;
    const int row0 = blockIdx.y * 128, col0 = blockIdx.x * 128;
    const int sr = tid >> 2;       // staging row within 64-row half
    const int sk = (tid & 3) * 8;  // staging k element offset

    f32x4 acc[4][4] = {};

    for (int k0 = 0; k0 < K; k0 += 32) {
        __syncthreads();  // previous iter's LDS reads done
        {
            const int koff = k0 + sk;
            int ra0 = row0 + sr;      if (ra0 > M - 1) ra0 = M - 1;
            int ra1 = row0 + 64 + sr; if (ra1 > M - 1) ra1 = M - 1;
            gl_lds16(&Ah[(size_t)ra0 * K + koff], &sAh[sr * 32 + sk]);
            gl_lds16(&Ah[(size_t)ra1 * K + koff], &sAh[(64 + sr) * 32 + sk]);
            gl_lds16(&Al[(size_t)ra0 * K + koff], &sAl[sr * 32 + sk]);
            gl_lds16(&Al[(size_t)ra1 * K + koff], &sAl[(64 + sr) * 32 + sk]);
            const size_t cb0 = (size_t)(col0 + sr) * K + koff;
            const size_t cb1 = (size_t)(col0 + 64 + sr) * K + koff;
            gl_lds16(&Bh[cb0], &sBh[sr * 32 + sk]);
            gl_lds16(&Bh[cb1], &sBh[(64 + sr) * 32 + sk]);
            gl_lds16(&Bl[cb0], &sBl[sr * 32 + sk]);
            gl_lds16(&Bl[cb1], &sBl[(64 + sr) * 32 + sk]);
        }
        __syncthreads();  // compiler drains vmcnt(0) before barrier

        s16x8 a_h[4], a_l[4], b_h[4], b_l[4];
#pragma unroll
        for (int m = 0; m < 4; m++) {
            const int r = (wr + m * 16 + ln) * 32 + kg;
            a_h[m] = *reinterpret_cast<const s16x8*>(&sAh[r]);
            a_l[m] = *reinterpret_cast<const s16x8*>(&sAl[r]);
        }
#pragma unroll
        for (int n = 0; n < 4; n++) {
            const int c = (wc + n * 16 + ln) * 32 + kg;
            b_h[n] = *reinterpret_cast<const s16x8*>(&sBh[c]);
            b_l[n] = *reinterpret_cast<const s16x8*>(&sBl[c]);
        }
#pragma unroll
        for (int m = 0; m < 4; m++)
#pragma unroll
            for (int n = 0; n < 4; n++) {
                mfma_bf16(acc[m][n], a_h[m], b_h[n]);
                mfma_bf16(acc[m][n], a_h[m], b_l[n]);
                mfma_bf16(acc[m][n], a_l[m], b_h[n]);
            }
    }

    asm volatile("s_nop 7\n\ts_nop 7");  // MFMA->VALU read hazard guard

#pragma unroll
    for (int n = 0; n < 4; n++) {
        const int col = col0 + wc + n * 16 + ln;
        const float bv = (EPI == 2) ? bias[col] : 0.0f;
#pragma unroll
        for (int m = 0; m < 4; m++) {
#pragma unroll
            for (int j = 0; j < 4; j++) {
                const int row = row0 + wr + m * 16 + lhi * 4 + j;
                if (row < M) {
                    float f = acc[m][n][j];
                    if (EPI == 2) f = fmaxf(f + bv, 0.0f);
                    const ushort_t h = f2bf(f);
                    const ushort_t l = f2bf(f - bf2f(h));
                    const size_t o = (size_t)row * N + col;
                    Ch[o] = h;
                    Cl[o] = l;
                }
            }
        }
    }
}

// ---------------------------------------------------------------------------
// Aggregation. INP: 0 = gather fp32 xf, 1 = gather bf16 pair (xh+xl).
// OUTM: 0 = fp32 out +bias+relu; 1 = split-pair out plain; 2 = split +bias+relu.
// ---------------------------------------------------------------------------
template <int M_, int TPB, int INP, int OUTM>
__global__ void k_agg(const float* __restrict__ xf,
                      const ushort_t* __restrict__ xh, const ushort_t* __restrict__ xl,
                      const float* __restrict__ dinv, const int* __restrict__ rp,
                      const int* __restrict__ es, const float* __restrict__ ew,
                      const float* __restrict__ bias,
                      float* __restrict__ of, ushort_t* __restrict__ oh,
                      ushort_t* __restrict__ ol) {
    constexpr int VEC = M_ / TPB;
    static_assert(VEC == 2 || VEC == 4, "");
    const int node = blockIdx.x;
    const int tid = threadIdx.x;
    __shared__ int s_src[64];
    __shared__ float s_w[64];

    const float di = dinv[node];
    const float sw = di * di;
    const size_t selfo = (size_t)node * M_ + tid * VEC;
    float acc[VEC];
    if constexpr (INP == 0) {
        if constexpr (VEC == 4) {
            float4 v = *reinterpret_cast<const float4*>(&xf[selfo]);
            acc[0] = v.x * sw; acc[1] = v.y * sw; acc[2] = v.z * sw; acc[3] = v.w * sw;
        } else {
            float2 v = *reinterpret_cast<const float2*>(&xf[selfo]);
            acc[0] = v.x * sw; acc[1] = v.y * sw;
        }
    } else {
        if constexpr (VEC == 4) {
            us4 vh = *reinterpret_cast<const us4*>(&xh[selfo]);
            us4 vl = *reinterpret_cast<const us4*>(&xl[selfo]);
#pragma unroll
            for (int j = 0; j < 4; j++) acc[j] = (bf2f(vh[j]) + bf2f(vl[j])) * sw;
        } else {
            us2 vh = *reinterpret_cast<const us2*>(&xh[selfo]);
            us2 vl = *reinterpret_cast<const us2*>(&xl[selfo]);
#pragma unroll
            for (int j = 0; j < 2; j++) acc[j] = (bf2f(vh[j]) + bf2f(vl[j])) * sw;
        }
    }

    const int beg = rp[node], end = rp[node + 1];
    for (int c = beg; c < end; c += 64) {
        const int m = min(64, end - c);
        __syncthreads();
        if (tid < m) { s_src[tid] = es[c + tid]; s_w[tid] = ew[c + tid]; }
        __syncthreads();
        for (int e = 0; e < m; e++) {
            const float w = s_w[e];
            const size_t o = (size_t)s_src[e] * M_ + tid * VEC;
            if constexpr (INP == 0) {
                if constexpr (VEC == 4) {
                    float4 v = *reinterpret_cast<const float4*>(&xf[o]);
                    acc[0] = fmaf(v.x, w, acc[0]); acc[1] = fmaf(v.y, w, acc[1]);
                    acc[2] = fmaf(v.z, w, acc[2]); acc[3] = fmaf(v.w, w, acc[3]);
                } else {
                    float2 v = *reinterpret_cast<const float2*>(&xf[o]);
                    acc[0] = fmaf(v.x, w, acc[0]); acc[1] = fmaf(v.y, w, acc[1]);
                }
            } else {
                if constexpr (VEC == 4) {
                    us4 vh = *reinterpret_cast<const us4*>(&xh[o]);
                    us4 vl = *reinterpret_cast<const us4*>(&xl[o]);
#pragma unroll
                    for (int j = 0; j < 4; j++) {
                        acc[j] = fmaf(bf2f(vh[j]), w, acc[j]);
                        acc[j] = fmaf(bf2f(vl[j]), w, acc[j]);
                    }
                } else {
                    us2 vh = *reinterpret_cast<const us2*>(&xh[o]);
                    us2 vl = *reinterpret_cast<const us2*>(&xl[o]);
#pragma unroll
                    for (int j = 0; j < 2; j++) {
                        acc[j] = fmaf(bf2f(vh[j]), w, acc[j]);
                        acc[j] = fmaf(bf2f(vl[j]), w, acc[j]);
                    }
                }
            }
        }
    }

#pragma unroll
    for (int j = 0; j < VEC; j++) {
        float f = acc[j];
        if constexpr (OUTM != 1) f = fmaxf(f + bias[tid * VEC + j], 0.0f);
        acc[j] = f;
    }
    if constexpr (OUTM == 0) {
        if constexpr (VEC == 4)
            *reinterpret_cast<float4*>(&of[selfo]) = make_float4(acc[0], acc[1], acc[2], acc[3]);
        else
            *reinterpret_cast<float2*>(&of[selfo]) = make_float2(acc[0], acc[1]);
    } else {
        ushort_t hh[VEC], ll[VEC];
#pragma unroll
        for (int j = 0; j < VEC; j++) {
            hh[j] = f2bf(acc[j]);
            ll[j] = f2bf(acc[j] - bf2f(hh[j]));
        }
        if constexpr (VEC == 4) {
            us4 h4 = {hh[0], hh[1], hh[2], hh[3]}, l4 = {ll[0], ll[1], ll[2], ll[3]};
            *reinterpret_cast<us4*>(&oh[selfo]) = h4;
            *reinterpret_cast<us4*>(&ol[selfo]) = l4;
        } else {
            us2 h2 = {hh[0], hh[1]}, l2 = {ll[0], ll[1]};
            *reinterpret_cast<us2*>(&oh[selfo]) = h2;
            *reinterpret_cast<us2*>(&ol[selfo]) = l2;
        }
    }
}

// ---------------------------------------------------------------------------
// Mean pool
// ---------------------------------------------------------------------------
__global__ void k_pool(const float* __restrict__ h, const int* __restrict__ batch,
                       float* __restrict__ out, float* __restrict__ pcnt) {
    const int node = blockIdx.x;
    const int f = threadIdx.x;  // 128
    const int g = batch[node];
    atomicAdd(&out[(size_t)g * DOUT + f], h[(size_t)node * DOUT + f]);
    if (f == 0) atomicAdd(&pcnt[g], 1.0f);
}

__global__ void k_pool_div(float* __restrict__ out, const float* __restrict__ pcnt) {
    out[(size_t)blockIdx.x * DOUT + threadIdx.x] /= fmaxf(pcnt[blockIdx.x], 1.0f);
}

// ---------------------------------------------------------------------------
extern "C" void kernel_launch(void* const* d_in, const int* in_sizes, int n_in,
                              void* d_out, int out_size, void* d_ws, size_t ws_size,
                              hipStream_t stream) {
    const float* x = (const float*)d_in[0];
    const int* ei = (const int*)d_in[1];
    const int* batch = (const int*)d_in[2];
    const float* b1 = (const float*)d_in[4];
    const float* b2 = (const float*)d_in[6];
    const float* b3 = (const float*)d_in[8];
    const float* b4 = (const float*)d_in[10];
    const float* b5 = (const float*)d_in[12];
    const int* src = ei;
    const int* dst = ei + NE;

    char* ws = (char*)d_ws;
    size_t off = 0;
    auto alloc = [&](size_t bytes) -> char* {
        char* p = ws + off;
        off = (off + bytes + 255) & ~(size_t)255;
        return p;
    };
    float* dinv = (float*)alloc(NN * 4);
    int* cnt    = (int*)alloc(NN * 4);
    int* rp     = (int*)alloc((NN + 1) * 4);
    int* fill   = (int*)alloc(NN * 4);
    int* es     = (int*)alloc(NE * 4);
    float* ewn  = (float*)alloc(NE * 4);
    ushort_t* wth = (ushort_t*)alloc(917504 * 2);
    ushort_t* wtl = (ushort_t*)alloc(917504 * 2);
    ushort_t* Xh = (ushort_t*)alloc((size_t)NN * DHID * 2);
    ushort_t* Xl = (ushort_t*)alloc((size_t)NN * DHID * 2);
    ushort_t* Yh = (ushort_t*)alloc((size_t)NN * DHID * 2);
    ushort_t* Yl = (ushort_t*)alloc((size_t)NN * DHID * 2);
    float* pcnt = (float*)alloc(NG * 4);
    float* hB = (float*)Yh;  // final fp32 activations (Y dead by then)
    (void)ws_size; (void)n_in; (void)in_sizes;

    hipMemsetAsync(cnt, 0, NN * 4, stream);
    hipMemsetAsync(fill, 0, NN * 4, stream);
    hipMemsetAsync(d_out, 0, (size_t)out_size * 4, stream);
    hipMemsetAsync(pcnt, 0, NG * 4, stream);

    // CSR + norm build
    k_edges_count<<<(NE + 255) / 256, 256, 0, stream>>>(dst, cnt, NE);
    k_dinv<<<(NN + 255) / 256, 256, 0, stream>>>(cnt, dinv, NN);
    k_scan2<<<1, 1024, 0, stream>>>(cnt, rp);
    k_scatter<<<(NE + 255) / 256, 256, 0, stream>>>(src, dst, dinv, rp, fill, es, ewn, NE);

    // Weight transpose+split (all layers)
    k_split_w<<<(917504 + 255) / 256, 256, 0, stream>>>(
        (const float*)d_in[3], (const float*)d_in[5], (const float*)d_in[7],
        (const float*)d_in[9], (const float*)d_in[11], wth, wtl);

    const int gy = (NN + 127) / 128;  // 79
    const ushort_t *w1h = wth, *w1l = wtl;
    const ushort_t *w2h = wth + 65536, *w2l = wtl + 65536;
    const ushort_t *w3h = wth + 327680, *w3l = wtl + 327680;
    const ushort_t *w4h = wth + 589824, *w4l = wtl + 589824;
    const ushort_t *w5h = wth + 851968, *w5l = wtl + 851968;

    // L1: agg(x) in 128-dim -> pair in X-front; GEMM1 (+b1+relu) -> Y
    k_agg<DIN, 64, 0, 1><<<NN, 64, 0, stream>>>(x, nullptr, nullptr, dinv, rp, es, ewn,
                                                nullptr, nullptr, Xh, Xl);
    k_mgemm<2><<<dim3(4, gy), 256, 0, stream>>>(Xh, Xl, w1h, w1l, b1, Yh, Yl, NN, DHID, DIN);

    // L2-4: GEMM (split out) -> X ; agg(+bias+relu, split out) -> Y
    k_mgemm<1><<<dim3(4, gy), 256, 0, stream>>>(Yh, Yl, w2h, w2l, nullptr, Xh, Xl, NN, DHID, DHID);
    k_agg<DHID, 128, 1, 2><<<NN, 128, 0, stream>>>(nullptr, Xh, Xl, dinv, rp, es, ewn, b2,
                                                   nullptr, Yh, Yl);
    k_mgemm<1><<<dim3(4, gy), 256, 0, stream>>>(Yh, Yl, w3h, w3l, nullptr, Xh, Xl, NN, DHID, DHID);
    k_agg<DHID, 128, 1, 2><<<NN, 128, 0, stream>>>(nullptr, Xh, Xl, dinv, rp, es, ewn, b3,
                                                   nullptr, Yh, Yl);
    k_mgemm<1><<<dim3(4, gy), 256, 0, stream>>>(Yh, Yl, w4h, w4l, nullptr, Xh, Xl, NN, DHID, DHID);
    k_agg<DHID, 128, 1, 2><<<NN, 128, 0, stream>>>(nullptr, Xh, Xl, dinv, rp, es, ewn, b4,
                                                   nullptr, Yh, Yl);

    // L5: GEMM (512->128, split out) -> X-front ; agg(+b5+relu, fp32 out) -> hB
    k_mgemm<1><<<dim3(1, gy), 256, 0, stream>>>(Yh, Yl, w5h, w5l, nullptr, Xh, Xl, NN, DOUT, DHID);
    k_agg<DOUT, 64, 1, 0><<<NN, 64, 0, stream>>>(nullptr, Xh, Xl, dinv, rp, es, ewn, b5,
                                                 hB, nullptr, nullptr);

    // Mean pool
    k_pool<<<NN, DOUT, 0, stream>>>(hB, batch, (float*)d_out, pcnt);
    k_pool_div<<<NG, DOUT, 0, stream>>>((float*)d_out, pcnt);
}

// Round 6
// 458.096 us; speedup vs baseline: 1.5424x; 1.0926x over previous
//
#include <hip/hip_runtime.h>
#include <stdint.h>

#define NN 10000
#define NE 150000
#define NG 64
#define DIN 128
#define DHID 512
#define DOUT 128

typedef float f32x4 __attribute__((ext_vector_type(4)));
typedef short s16x8 __attribute__((ext_vector_type(8)));
typedef unsigned short us4 __attribute__((ext_vector_type(4)));
typedef unsigned short us2 __attribute__((ext_vector_type(2)));
typedef unsigned short ushort_t;

// ---------------------------------------------------------------------------
// bf16 helpers (RNE)
// ---------------------------------------------------------------------------
__device__ __forceinline__ ushort_t f2bf(float f) {
    unsigned u = __float_as_uint(f);
    u += 0x7FFFu + ((u >> 16) & 1u);
    return (ushort_t)(u >> 16);
}
__device__ __forceinline__ float bf2f(ushort_t s) {
    return __uint_as_float(((unsigned)s) << 16);
}

__device__ __forceinline__ void gl_lds16(const void* g, void* l) {
    __builtin_amdgcn_global_load_lds(
        (const __attribute__((address_space(1))) unsigned int*)g,
        (__attribute__((address_space(3))) unsigned int*)l, 16, 0, 0);
}

__device__ __forceinline__ void mfma_bf16(f32x4& d, s16x8 a, s16x8 b) {
    asm("v_mfma_f32_16x16x32_bf16 %0, %1, %2, %0" : "+v"(d) : "v"(a), "v"(b));
}

// ---------------------------------------------------------------------------
// CSR build
// ---------------------------------------------------------------------------
__global__ void k_edges_count(const int* __restrict__ dst, int* __restrict__ cnt, int E) {
    int e = blockIdx.x * blockDim.x + threadIdx.x;
    if (e < E) atomicAdd(&cnt[dst[e]], 1);
}

__global__ void k_dinv(const int* __restrict__ cnt, float* __restrict__ dinv, int n) {
    int i = blockIdx.x * blockDim.x + threadIdx.x;
    if (i < n) dinv[i] = rsqrtf(1.0f + (float)cnt[i]);  // +1 self loop
}

// 1024-thread single-block exclusive scan of cnt[0..NN) -> rp[0..NN]
__global__ void k_scan2(const int* __restrict__ cnt, int* __restrict__ rp) {
    const int C = 10;  // 1024*10 >= 10001
    const int t = threadIdx.x;
    const int lane = t & 63, w = t >> 6;
    const int base = t * C;
    int v[C];
    int s = 0;
#pragma unroll
    for (int j = 0; j < C; j++) {
        int i = base + j;
        v[j] = (i < NN) ? cnt[i] : 0;
        s += v[j];
    }
    int sc = s;
#pragma unroll
    for (int off = 1; off < 64; off <<= 1) {
        int tv = __shfl_up(sc, off);
        if (lane >= off) sc += tv;
    }
    __shared__ int wsum[16], woff[16];
    if (lane == 63) wsum[w] = sc;
    __syncthreads();
    if (t == 0) {
        int c = 0;
#pragma unroll
        for (int k = 0; k < 16; k++) { woff[k] = c; c += wsum[k]; }
    }
    __syncthreads();
    int pre = woff[w] + (sc - s);
#pragma unroll
    for (int j = 0; j < C; j++) {
        int i = base + j;
        if (i <= NN) rp[i] = pre;
        pre += v[j];
    }
}

__global__ void k_scatter(const int* __restrict__ src, const int* __restrict__ dst,
                          const float* __restrict__ dinv, const int* __restrict__ rp,
                          int* __restrict__ fill, int* __restrict__ es,
                          float* __restrict__ ew, int E) {
    int e = blockIdx.x * blockDim.x + threadIdx.x;
    if (e < E) {
        int d = dst[e], s = src[e];
        int p = rp[d] + atomicAdd(&fill[d], 1);
        es[p] = s;
        ew[p] = dinv[s] * dinv[d];
    }
}

// ---------------------------------------------------------------------------
// Weight transpose + bf16 hi/lo split (all 5 layers, one launch)
// ---------------------------------------------------------------------------
__global__ void k_split_w(const float* __restrict__ W1, const float* __restrict__ W2,
                          const float* __restrict__ W3, const float* __restrict__ W4,
                          const float* __restrict__ W5,
                          ushort_t* __restrict__ th, ushort_t* __restrict__ tl) {
    int t = blockIdx.x * blockDim.x + threadIdx.x;
    const float* W;
    int K, Mw, off, r;
    if (t < 65536)       { W = W1; K = 128; Mw = 512; off = 0;      r = t; }
    else if (t < 327680) { W = W2; K = 512; Mw = 512; off = 65536;  r = t - 65536; }
    else if (t < 589824) { W = W3; K = 512; Mw = 512; off = 327680; r = t - 327680; }
    else if (t < 851968) { W = W4; K = 512; Mw = 512; off = 589824; r = t - 589824; }
    else if (t < 917504) { W = W5; K = 512; Mw = 128; off = 851968; r = t - 851968; }
    else return;
    const int k = r / Mw, m = r % Mw;
    const float f = W[r];
    const ushort_t h = f2bf(f);
    const ushort_t l = f2bf(f - bf2f(h));
    const int o = off + m * K + k;
    th[o] = h;
    tl[o] = l;
}

// ---------------------------------------------------------------------------
// bf16x3 split MFMA GEMM: C[M][N] = (Ah+Al)[M][K] @ (Bh+Bl)^T  (Bt is [N][K])
// 128x128 tile, BK=32, 4 waves (2x2 of 64x64), 16x16x32 MFMA.
// EPI: 0 = fp32 C out; 2 = bias+relu+split-pair out.
// ---------------------------------------------------------------------------
template <int EPI>
__global__ __launch_bounds__(256, 2) void k_mgemm(
    const ushort_t* __restrict__ Ah, const ushort_t* __restrict__ Al,
    const ushort_t* __restrict__ Bh, const ushort_t* __restrict__ Bl,
    const float* __restrict__ bias,
    ushort_t* __restrict__ Ch, ushort_t* __restrict__ Cl, float* __restrict__ Cf,
    const int M, const int N, const int K) {
    __shared__ ushort_t sAh[128 * 32], sAl[128 * 32], sBh[128 * 32], sBl[128 * 32];
    const int tid = threadIdx.x;
    const int lane = tid & 63, wv = tid >> 6;
    const int ln = lane & 15, lhi = lane >> 4;
    const int kg = lhi * 8;
    const int wr = (wv >> 1) * 64, wc = (wv & 1) * 64;
    const int row0 = blockIdx.y * 128, col0 = blockIdx.x * 128;
    const int sr = tid >> 2;
    const int sk = (tid & 3) * 8;

    f32x4 acc[4][4] = {};

    for (int k0 = 0; k0 < K; k0 += 32) {
        __syncthreads();
        {
            const int koff = k0 + sk;
            int ra0 = row0 + sr;      if (ra0 > M - 1) ra0 = M - 1;
            int ra1 = row0 + 64 + sr; if (ra1 > M - 1) ra1 = M - 1;
            gl_lds16(&Ah[(size_t)ra0 * K + koff], &sAh[sr * 32 + sk]);
            gl_lds16(&Ah[(size_t)ra1 * K + koff], &sAh[(64 + sr) * 32 + sk]);
            gl_lds16(&Al[(size_t)ra0 * K + koff], &sAl[sr * 32 + sk]);
            gl_lds16(&Al[(size_t)ra1 * K + koff], &sAl[(64 + sr) * 32 + sk]);
            const size_t cb0 = (size_t)(col0 + sr) * K + koff;
            const size_t cb1 = (size_t)(col0 + 64 + sr) * K + koff;
            gl_lds16(&Bh[cb0], &sBh[sr * 32 + sk]);
            gl_lds16(&Bh[cb1], &sBh[(64 + sr) * 32 + sk]);
            gl_lds16(&Bl[cb0], &sBl[sr * 32 + sk]);
            gl_lds16(&Bl[cb1], &sBl[(64 + sr) * 32 + sk]);
        }
        __syncthreads();

        s16x8 a_h[4], a_l[4], b_h[4], b_l[4];
#pragma unroll
        for (int m = 0; m < 4; m++) {
            const int r = (wr + m * 16 + ln) * 32 + kg;
            a_h[m] = *reinterpret_cast<const s16x8*>(&sAh[r]);
            a_l[m] = *reinterpret_cast<const s16x8*>(&sAl[r]);
        }
#pragma unroll
        for (int n = 0; n < 4; n++) {
            const int c = (wc + n * 16 + ln) * 32 + kg;
            b_h[n] = *reinterpret_cast<const s16x8*>(&sBh[c]);
            b_l[n] = *reinterpret_cast<const s16x8*>(&sBl[c]);
        }
#pragma unroll
        for (int m = 0; m < 4; m++)
#pragma unroll
            for (int n = 0; n < 4; n++) {
                mfma_bf16(acc[m][n], a_h[m], b_h[n]);
                mfma_bf16(acc[m][n], a_h[m], b_l[n]);
                mfma_bf16(acc[m][n], a_l[m], b_h[n]);
            }
    }

    asm volatile("s_nop 7\n\ts_nop 7");  // MFMA->VALU hazard guard

#pragma unroll
    for (int n = 0; n < 4; n++) {
        const int col = col0 + wc + n * 16 + ln;
        const float bv = (EPI == 2) ? bias[col] : 0.0f;
#pragma unroll
        for (int m = 0; m < 4; m++) {
#pragma unroll
            for (int j = 0; j < 4; j++) {
                const int row = row0 + wr + m * 16 + lhi * 4 + j;
                if (row < M) {
                    float f = acc[m][n][j];
                    const size_t o = (size_t)row * N + col;
                    if constexpr (EPI == 2) {
                        f = fmaxf(f + bv, 0.0f);
                        const ushort_t h = f2bf(f);
                        Ch[o] = h;
                        Cl[o] = f2bf(f - bf2f(h));
                    } else {
                        Cf[o] = f;
                    }
                }
            }
        }
    }
}

// ---------------------------------------------------------------------------
// Aggregation over fp32 input. OUTM: 0 = fp32 out +bias+relu;
// 1 = split-pair out plain; 2 = split-pair out +bias+relu.
// ---------------------------------------------------------------------------
template <int M_, int TPB, int OUTM>
__global__ void k_agg(const float* __restrict__ xf, const float* __restrict__ dinv,
                      const int* __restrict__ rp, const int* __restrict__ es,
                      const float* __restrict__ ew, const float* __restrict__ bias,
                      float* __restrict__ of, ushort_t* __restrict__ oh,
                      ushort_t* __restrict__ ol) {
    constexpr int VEC = M_ / TPB;
    static_assert(VEC == 2 || VEC == 4, "");
    const int node = blockIdx.x;
    const int tid = threadIdx.x;
    __shared__ int s_src[64];
    __shared__ float s_w[64];

    const float di = dinv[node];
    const float sw = di * di;
    const size_t selfo = (size_t)node * M_ + tid * VEC;
    float acc[VEC];
    if constexpr (VEC == 4) {
        float4 v = *reinterpret_cast<const float4*>(&xf[selfo]);
        acc[0] = v.x * sw; acc[1] = v.y * sw; acc[2] = v.z * sw; acc[3] = v.w * sw;
    } else {
        float2 v = *reinterpret_cast<const float2*>(&xf[selfo]);
        acc[0] = v.x * sw; acc[1] = v.y * sw;
    }

    const int beg = rp[node], end = rp[node + 1];
    for (int c = beg; c < end; c += 64) {
        const int m = min(64, end - c);
        __syncthreads();
        if (tid < m) { s_src[tid] = es[c + tid]; s_w[tid] = ew[c + tid]; }
        __syncthreads();
        for (int e = 0; e < m; e++) {
            const float w = s_w[e];
            const size_t o = (size_t)s_src[e] * M_ + tid * VEC;
            if constexpr (VEC == 4) {
                float4 v = *reinterpret_cast<const float4*>(&xf[o]);
                acc[0] = fmaf(v.x, w, acc[0]); acc[1] = fmaf(v.y, w, acc[1]);
                acc[2] = fmaf(v.z, w, acc[2]); acc[3] = fmaf(v.w, w, acc[3]);
            } else {
                float2 v = *reinterpret_cast<const float2*>(&xf[o]);
                acc[0] = fmaf(v.x, w, acc[0]); acc[1] = fmaf(v.y, w, acc[1]);
            }
        }
    }

#pragma unroll
    for (int j = 0; j < VEC; j++) {
        float f = acc[j];
        if constexpr (OUTM != 1) f = fmaxf(f + bias[tid * VEC + j], 0.0f);
        acc[j] = f;
    }
    if constexpr (OUTM == 0) {
        if constexpr (VEC == 4)
            *reinterpret_cast<float4*>(&of[selfo]) = make_float4(acc[0], acc[1], acc[2], acc[3]);
        else
            *reinterpret_cast<float2*>(&of[selfo]) = make_float2(acc[0], acc[1]);
    } else {
        ushort_t hh[VEC], ll[VEC];
#pragma unroll
        for (int j = 0; j < VEC; j++) {
            hh[j] = f2bf(acc[j]);
            ll[j] = f2bf(acc[j] - bf2f(hh[j]));
        }
        if constexpr (VEC == 4) {
            us4 h4 = {hh[0], hh[1], hh[2], hh[3]}, l4 = {ll[0], ll[1], ll[2], ll[3]};
            *reinterpret_cast<us4*>(&oh[selfo]) = h4;
            *reinterpret_cast<us4*>(&ol[selfo]) = l4;
        } else {
            us2 h2 = {hh[0], hh[1]}, l2 = {ll[0], ll[1]};
            *reinterpret_cast<us2*>(&oh[selfo]) = h2;
            *reinterpret_cast<us2*>(&ol[selfo]) = l2;
        }
    }
}

// ---------------------------------------------------------------------------
// Mean pool: batch is SORTED -> per-graph contiguous ranges, no atomics.
// ---------------------------------------------------------------------------
__global__ void k_gbounds(const int* __restrict__ batch, int* __restrict__ gstart) {
    const int g = threadIdx.x;  // 0..64
    if (g > NG) return;
    int lo = 0, hi = NN;  // first index with batch[i] >= g
    while (lo < hi) {
        int mid = (lo + hi) >> 1;
        if (batch[mid] < g) lo = mid + 1; else hi = mid;
    }
    gstart[g] = lo;
}

__global__ void k_pool2(const float* __restrict__ h, const int* __restrict__ gstart,
                        float* __restrict__ out) {
    const int g = blockIdx.x;
    const int f = threadIdx.x;  // 128
    const int s = gstart[g], e = gstart[g + 1];
    float acc = 0.0f;
    for (int i = s; i < e; i++) acc += h[(size_t)i * DOUT + f];
    out[(size_t)g * DOUT + f] = acc / fmaxf((float)(e - s), 1.0f);
}

// ---------------------------------------------------------------------------
extern "C" void kernel_launch(void* const* d_in, const int* in_sizes, int n_in,
                              void* d_out, int out_size, void* d_ws, size_t ws_size,
                              hipStream_t stream) {
    const float* x = (const float*)d_in[0];
    const int* ei = (const int*)d_in[1];
    const int* batch = (const int*)d_in[2];
    const float* b1 = (const float*)d_in[4];
    const float* b2 = (const float*)d_in[6];
    const float* b3 = (const float*)d_in[8];
    const float* b4 = (const float*)d_in[10];
    const float* b5 = (const float*)d_in[12];
    const int* src = ei;
    const int* dst = ei + NE;

    char* ws = (char*)d_ws;
    size_t off = 0;
    auto alloc = [&](size_t bytes) -> char* {
        char* p = ws + off;
        off = (off + bytes + 255) & ~(size_t)255;
        return p;
    };
    float* dinv = (float*)alloc(NN * 4);
    int* cnt    = (int*)alloc(NN * 4);
    int* rp     = (int*)alloc((NN + 1) * 4);
    int* fill   = (int*)alloc(NN * 4);
    int* es     = (int*)alloc(NE * 4);
    float* ewn  = (float*)alloc(NE * 4);
    int* gstart = (int*)alloc((NG + 1) * 4);
    ushort_t* wth = (ushort_t*)alloc(917504 * 2);
    ushort_t* wtl = (ushort_t*)alloc(917504 * 2);
    ushort_t* Xh = (ushort_t*)alloc((size_t)NN * DHID * 2);
    ushort_t* Xl = (ushort_t*)alloc((size_t)NN * DHID * 2);
    ushort_t* Yh = (ushort_t*)alloc((size_t)NN * DHID * 2);
    ushort_t* Yl = (ushort_t*)alloc((size_t)NN * DHID * 2);
    float* hF = (float*)alloc((size_t)NN * DHID * 4);  // fp32 GEMM out
    float* hOut = (float*)Xh;  // fp32 final activations (X dead by L5)
    (void)ws_size; (void)n_in; (void)in_sizes;

    hipMemsetAsync(cnt, 0, NN * 4, stream);
    hipMemsetAsync(fill, 0, NN * 4, stream);

    // CSR + norm build
    k_edges_count<<<(NE + 255) / 256, 256, 0, stream>>>(dst, cnt, NE);
    k_dinv<<<(NN + 255) / 256, 256, 0, stream>>>(cnt, dinv, NN);
    k_scan2<<<1, 1024, 0, stream>>>(cnt, rp);
    k_scatter<<<(NE + 255) / 256, 256, 0, stream>>>(src, dst, dinv, rp, fill, es, ewn, NE);
    k_gbounds<<<1, 128, 0, stream>>>(batch, gstart);

    // Weight transpose+split
    k_split_w<<<(917504 + 255) / 256, 256, 0, stream>>>(
        (const float*)d_in[3], (const float*)d_in[5], (const float*)d_in[7],
        (const float*)d_in[9], (const float*)d_in[11], wth, wtl);

    const int gy = (NN + 127) / 128;  // 79
    const ushort_t *w1h = wth, *w1l = wtl;
    const ushort_t *w2h = wth + 65536, *w2l = wtl + 65536;
    const ushort_t *w3h = wth + 327680, *w3l = wtl + 327680;
    const ushort_t *w4h = wth + 589824, *w4l = wtl + 589824;
    const ushort_t *w5h = wth + 851968, *w5l = wtl + 851968;

    // L1: agg(x, 128-dim) -> pair X ; GEMM1(+b1+relu) -> pair Y
    k_agg<DIN, 64, 1><<<NN, 64, 0, stream>>>(x, dinv, rp, es, ewn, nullptr,
                                             nullptr, Xh, Xl);
    k_mgemm<2><<<dim3(4, gy), 256, 0, stream>>>(Xh, Xl, w1h, w1l, b1, Yh, Yl, nullptr,
                                                NN, DHID, DIN);

    // L2-4: GEMM (fp32 out) -> hF ; agg(fp32 gather, +bias+relu, pair out) -> Y
    k_mgemm<0><<<dim3(4, gy), 256, 0, stream>>>(Yh, Yl, w2h, w2l, nullptr, nullptr, nullptr, hF,
                                                NN, DHID, DHID);
    k_agg<DHID, 128, 2><<<NN, 128, 0, stream>>>(hF, dinv, rp, es, ewn, b2, nullptr, Yh, Yl);
    k_mgemm<0><<<dim3(4, gy), 256, 0, stream>>>(Yh, Yl, w3h, w3l, nullptr, nullptr, nullptr, hF,
                                                NN, DHID, DHID);
    k_agg<DHID, 128, 2><<<NN, 128, 0, stream>>>(hF, dinv, rp, es, ewn, b3, nullptr, Yh, Yl);
    k_mgemm<0><<<dim3(4, gy), 256, 0, stream>>>(Yh, Yl, w4h, w4l, nullptr, nullptr, nullptr, hF,
                                                NN, DHID, DHID);
    k_agg<DHID, 128, 2><<<NN, 128, 0, stream>>>(hF, dinv, rp, es, ewn, b4, nullptr, Yh, Yl);

    // L5: GEMM (512->128, fp32 out) -> hF ; agg(+b5+relu, fp32 out) -> hOut
    k_mgemm<0><<<dim3(1, gy), 256, 0, stream>>>(Yh, Yl, w5h, w5l, nullptr, nullptr, nullptr, hF,
                                                NN, DOUT, DHID);
    k_agg<DOUT, 64, 0><<<NN, 64, 0, stream>>>(hF, dinv, rp, es, ewn, b5, hOut, nullptr, nullptr);

    // Mean pool (deterministic, no atomics)
    k_pool2<<<NG, DOUT, 0, stream>>>(hOut, gstart, (float*)d_out);
}

// Round 7
// 416.734 us; speedup vs baseline: 1.6955x; 1.0993x over previous
//
#include <hip/hip_runtime.h>
#include <stdint.h>

#define NN 10000
#define NE 150000
#define NG 64
#define DIN 128
#define DHID 512
#define DOUT 128
#define POOL_P 16  // pool partitions per graph

typedef float f32x4 __attribute__((ext_vector_type(4)));
typedef short s16x8 __attribute__((ext_vector_type(8)));
typedef unsigned short us4 __attribute__((ext_vector_type(4)));
typedef unsigned short us2 __attribute__((ext_vector_type(2)));
typedef unsigned short ushort_t;

// ---------------------------------------------------------------------------
// bf16 helpers (RNE)
// ---------------------------------------------------------------------------
__device__ __forceinline__ ushort_t f2bf(float f) {
    unsigned u = __float_as_uint(f);
    u += 0x7FFFu + ((u >> 16) & 1u);
    return (ushort_t)(u >> 16);
}
__device__ __forceinline__ float bf2f(ushort_t s) {
    return __uint_as_float(((unsigned)s) << 16);
}

__device__ __forceinline__ void gl_lds16(const void* g, void* l) {
    __builtin_amdgcn_global_load_lds(
        (const __attribute__((address_space(1))) unsigned int*)g,
        (__attribute__((address_space(3))) unsigned int*)l, 16, 0, 0);
}

__device__ __forceinline__ void mfma_bf16(f32x4& d, s16x8 a, s16x8 b) {
    asm("v_mfma_f32_16x16x32_bf16 %0, %1, %2, %0" : "+v"(d) : "v"(a), "v"(b));
}

// ---------------------------------------------------------------------------
// CSR build
// ---------------------------------------------------------------------------
__global__ void k_edges_count(const int* __restrict__ dst, int* __restrict__ cnt, int E) {
    int e = blockIdx.x * blockDim.x + threadIdx.x;
    if (e < E) atomicAdd(&cnt[dst[e]], 1);
}

__global__ void k_dinv(const int* __restrict__ cnt, float* __restrict__ dinv, int n) {
    int i = blockIdx.x * blockDim.x + threadIdx.x;
    if (i < n) dinv[i] = rsqrtf(1.0f + (float)cnt[i]);  // +1 self loop
}

// 1024-thread single-block exclusive scan of cnt[0..NN) -> rp[0..NN]
__global__ void k_scan2(const int* __restrict__ cnt, int* __restrict__ rp) {
    const int C = 10;  // 1024*10 >= 10001
    const int t = threadIdx.x;
    const int lane = t & 63, w = t >> 6;
    const int base = t * C;
    int v[C];
    int s = 0;
#pragma unroll
    for (int j = 0; j < C; j++) {
        int i = base + j;
        v[j] = (i < NN) ? cnt[i] : 0;
        s += v[j];
    }
    int sc = s;
#pragma unroll
    for (int off = 1; off < 64; off <<= 1) {
        int tv = __shfl_up(sc, off);
        if (lane >= off) sc += tv;
    }
    __shared__ int wsum[16], woff[16];
    if (lane == 63) wsum[w] = sc;
    __syncthreads();
    if (t == 0) {
        int c = 0;
#pragma unroll
        for (int k = 0; k < 16; k++) { woff[k] = c; c += wsum[k]; }
    }
    __syncthreads();
    int pre = woff[w] + (sc - s);
#pragma unroll
    for (int j = 0; j < C; j++) {
        int i = base + j;
        if (i <= NN) rp[i] = pre;
        pre += v[j];
    }
}

__global__ void k_scatter(const int* __restrict__ src, const int* __restrict__ dst,
                          const float* __restrict__ dinv, const int* __restrict__ rp,
                          int* __restrict__ fill, int* __restrict__ es,
                          float* __restrict__ ew, int E) {
    int e = blockIdx.x * blockDim.x + threadIdx.x;
    if (e < E) {
        int d = dst[e], s = src[e];
        int p = rp[d] + atomicAdd(&fill[d], 1);
        es[p] = s;
        ew[p] = dinv[s] * dinv[d];
    }
}

// ---------------------------------------------------------------------------
// Weight transpose + bf16 hi/lo split (all 5 layers, one launch)
// ---------------------------------------------------------------------------
__global__ void k_split_w(const float* __restrict__ W1, const float* __restrict__ W2,
                          const float* __restrict__ W3, const float* __restrict__ W4,
                          const float* __restrict__ W5,
                          ushort_t* __restrict__ th, ushort_t* __restrict__ tl) {
    int t = blockIdx.x * blockDim.x + threadIdx.x;
    const float* W;
    int K, Mw, off, r;
    if (t < 65536)       { W = W1; K = 128; Mw = 512; off = 0;      r = t; }
    else if (t < 327680) { W = W2; K = 512; Mw = 512; off = 65536;  r = t - 65536; }
    else if (t < 589824) { W = W3; K = 512; Mw = 512; off = 327680; r = t - 327680; }
    else if (t < 851968) { W = W4; K = 512; Mw = 512; off = 589824; r = t - 589824; }
    else if (t < 917504) { W = W5; K = 512; Mw = 128; off = 851968; r = t - 851968; }
    else return;
    const int k = r / Mw, m = r % Mw;
    const float f = W[r];
    const ushort_t h = f2bf(f);
    const ushort_t l = f2bf(f - bf2f(h));
    const int o = off + m * K + k;
    th[o] = h;
    tl[o] = l;
}

// ---------------------------------------------------------------------------
// bf16x3 split MFMA GEMM: C[M][N] = (Ah+Al)[M][K] @ (Bh+Bl)^T  (Bt is [N][K])
// 128x128 tile, BK=32, 4 waves (2x2 of 64x64), 16x16x32 MFMA.
// EPI: 0 = fp32 C out; 2 = bias+relu+split-pair out.
// ---------------------------------------------------------------------------
template <int EPI>
__global__ __launch_bounds__(256, 2) void k_mgemm(
    const ushort_t* __restrict__ Ah, const ushort_t* __restrict__ Al,
    const ushort_t* __restrict__ Bh, const ushort_t* __restrict__ Bl,
    const float* __restrict__ bias,
    ushort_t* __restrict__ Ch, ushort_t* __restrict__ Cl, float* __restrict__ Cf,
    const int M, const int N, const int K) {
    __shared__ ushort_t sAh[128 * 32], sAl[128 * 32], sBh[128 * 32], sBl[128 * 32];
    const int tid = threadIdx.x;
    const int lane = tid & 63, wv = tid >> 6;
    const int ln = lane & 15, lhi = lane >> 4;
    const int kg = lhi * 8;
    const int wr = (wv >> 1) * 64, wc = (wv & 1) * 64;
    const int row0 = blockIdx.y * 128, col0 = blockIdx.x * 128;
    const int sr = tid >> 2;
    const int sk = (tid & 3) * 8;

    f32x4 acc[4][4] = {};

    for (int k0 = 0; k0 < K; k0 += 32) {
        __syncthreads();
        {
            const int koff = k0 + sk;
            int ra0 = row0 + sr;      if (ra0 > M - 1) ra0 = M - 1;
            int ra1 = row0 + 64 + sr; if (ra1 > M - 1) ra1 = M - 1;
            gl_lds16(&Ah[(size_t)ra0 * K + koff], &sAh[sr * 32 + sk]);
            gl_lds16(&Ah[(size_t)ra1 * K + koff], &sAh[(64 + sr) * 32 + sk]);
            gl_lds16(&Al[(size_t)ra0 * K + koff], &sAl[sr * 32 + sk]);
            gl_lds16(&Al[(size_t)ra1 * K + koff], &sAl[(64 + sr) * 32 + sk]);
            const size_t cb0 = (size_t)(col0 + sr) * K + koff;
            const size_t cb1 = (size_t)(col0 + 64 + sr) * K + koff;
            gl_lds16(&Bh[cb0], &sBh[sr * 32 + sk]);
            gl_lds16(&Bh[cb1], &sBh[(64 + sr) * 32 + sk]);
            gl_lds16(&Bl[cb0], &sBl[sr * 32 + sk]);
            gl_lds16(&Bl[cb1], &sBl[(64 + sr) * 32 + sk]);
        }
        __syncthreads();

        s16x8 a_h[4], a_l[4], b_h[4], b_l[4];
#pragma unroll
        for (int m = 0; m < 4; m++) {
            const int r = (wr + m * 16 + ln) * 32 + kg;
            a_h[m] = *reinterpret_cast<const s16x8*>(&sAh[r]);
            a_l[m] = *reinterpret_cast<const s16x8*>(&sAl[r]);
        }
#pragma unroll
        for (int n = 0; n < 4; n++) {
            const int c = (wc + n * 16 + ln) * 32 + kg;
            b_h[n] = *reinterpret_cast<const s16x8*>(&sBh[c]);
            b_l[n] = *reinterpret_cast<const s16x8*>(&sBl[c]);
        }
#pragma unroll
        for (int m = 0; m < 4; m++)
#pragma unroll
            for (int n = 0; n < 4; n++) {
                mfma_bf16(acc[m][n], a_h[m], b_h[n]);
                mfma_bf16(acc[m][n], a_h[m], b_l[n]);
                mfma_bf16(acc[m][n], a_l[m], b_h[n]);
            }
    }

    asm volatile("s_nop 7\n\ts_nop 7");  // MFMA->VALU hazard guard

#pragma unroll
    for (int n = 0; n < 4; n++) {
        const int col = col0 + wc + n * 16 + ln;
        const float bv = (EPI == 2) ? bias[col] : 0.0f;
#pragma unroll
        for (int m = 0; m < 4; m++) {
#pragma unroll
            for (int j = 0; j < 4; j++) {
                const int row = row0 + wr + m * 16 + lhi * 4 + j;
                if (row < M) {
                    float f = acc[m][n][j];
                    const size_t o = (size_t)row * N + col;
                    if constexpr (EPI == 2) {
                        f = fmaxf(f + bv, 0.0f);
                        const ushort_t h = f2bf(f);
                        Ch[o] = h;
                        Cl[o] = f2bf(f - bf2f(h));
                    } else {
                        Cf[o] = f;
                    }
                }
            }
        }
    }
}

// ---------------------------------------------------------------------------
// Aggregation over fp32 input. OUTM: 0 = fp32 out +bias+relu;
// 1 = split-pair out plain; 2 = split-pair out +bias+relu.
// ---------------------------------------------------------------------------
template <int M_, int TPB, int OUTM>
__global__ void k_agg(const float* __restrict__ xf, const float* __restrict__ dinv,
                      const int* __restrict__ rp, const int* __restrict__ es,
                      const float* __restrict__ ew, const float* __restrict__ bias,
                      float* __restrict__ of, ushort_t* __restrict__ oh,
                      ushort_t* __restrict__ ol) {
    constexpr int VEC = M_ / TPB;
    static_assert(VEC == 2 || VEC == 4, "");
    const int node = blockIdx.x;
    const int tid = threadIdx.x;
    __shared__ int s_src[64];
    __shared__ float s_w[64];

    const float di = dinv[node];
    const float sw = di * di;
    const size_t selfo = (size_t)node * M_ + tid * VEC;
    float acc[VEC];
    if constexpr (VEC == 4) {
        float4 v = *reinterpret_cast<const float4*>(&xf[selfo]);
        acc[0] = v.x * sw; acc[1] = v.y * sw; acc[2] = v.z * sw; acc[3] = v.w * sw;
    } else {
        float2 v = *reinterpret_cast<const float2*>(&xf[selfo]);
        acc[0] = v.x * sw; acc[1] = v.y * sw;
    }

    const int beg = rp[node], end = rp[node + 1];
    for (int c = beg; c < end; c += 64) {
        const int m = min(64, end - c);
        __syncthreads();
        if (tid < m) { s_src[tid] = es[c + tid]; s_w[tid] = ew[c + tid]; }
        __syncthreads();
        for (int e = 0; e < m; e++) {
            const float w = s_w[e];
            const size_t o = (size_t)s_src[e] * M_ + tid * VEC;
            if constexpr (VEC == 4) {
                float4 v = *reinterpret_cast<const float4*>(&xf[o]);
                acc[0] = fmaf(v.x, w, acc[0]); acc[1] = fmaf(v.y, w, acc[1]);
                acc[2] = fmaf(v.z, w, acc[2]); acc[3] = fmaf(v.w, w, acc[3]);
            } else {
                float2 v = *reinterpret_cast<const float2*>(&xf[o]);
                acc[0] = fmaf(v.x, w, acc[0]); acc[1] = fmaf(v.y, w, acc[1]);
            }
        }
    }

#pragma unroll
    for (int j = 0; j < VEC; j++) {
        float f = acc[j];
        if constexpr (OUTM != 1) f = fmaxf(f + bias[tid * VEC + j], 0.0f);
        acc[j] = f;
    }
    if constexpr (OUTM == 0) {
        if constexpr (VEC == 4)
            *reinterpret_cast<float4*>(&of[selfo]) = make_float4(acc[0], acc[1], acc[2], acc[3]);
        else
            *reinterpret_cast<float2*>(&of[selfo]) = make_float2(acc[0], acc[1]);
    } else {
        ushort_t hh[VEC], ll[VEC];
#pragma unroll
        for (int j = 0; j < VEC; j++) {
            hh[j] = f2bf(acc[j]);
            ll[j] = f2bf(acc[j] - bf2f(hh[j]));
        }
        if constexpr (VEC == 4) {
            us4 h4 = {hh[0], hh[1], hh[2], hh[3]}, l4 = {ll[0], ll[1], ll[2], ll[3]};
            *reinterpret_cast<us4*>(&oh[selfo]) = h4;
            *reinterpret_cast<us4*>(&ol[selfo]) = l4;
        } else {
            us2 h2 = {hh[0], hh[1]}, l2 = {ll[0], ll[1]};
            *reinterpret_cast<us2*>(&oh[selfo]) = h2;
            *reinterpret_cast<us2*>(&ol[selfo]) = l2;
        }
    }
}

// ---------------------------------------------------------------------------
// Mean pool: batch is SORTED -> per-graph contiguous ranges, no atomics.
// Two-stage partition reduce for occupancy (k_pool2 was 1% occupancy, 45.8us).
// ---------------------------------------------------------------------------
__global__ void k_gbounds(const int* __restrict__ batch, int* __restrict__ gstart) {
    const int g = threadIdx.x;  // 0..64
    if (g > NG) return;
    int lo = 0, hi = NN;  // first index with batch[i] >= g
    while (lo < hi) {
        int mid = (lo + hi) >> 1;
        if (batch[mid] < g) lo = mid + 1; else hi = mid;
    }
    gstart[g] = lo;
}

// Stage A: grid (NG, POOL_P), 128 thr. partial[(g*POOL_P+p)*DOUT + f]
__global__ void k_pool_part(const float* __restrict__ h, const int* __restrict__ gstart,
                            float* __restrict__ partial) {
    const int g = blockIdx.x, p = blockIdx.y;
    const int f = threadIdx.x;  // 128
    const int s = gstart[g], e = gstart[g + 1];
    const int len = e - s;
    const int chunk = (len + POOL_P - 1) / POOL_P;
    const int i0 = s + p * chunk;
    const int i1 = min(i0 + chunk, e);
    float a0 = 0.f, a1 = 0.f, a2 = 0.f, a3 = 0.f;
    int i = i0;
    for (; i + 3 < i1; i += 4) {
        a0 += h[(size_t)(i + 0) * DOUT + f];
        a1 += h[(size_t)(i + 1) * DOUT + f];
        a2 += h[(size_t)(i + 2) * DOUT + f];
        a3 += h[(size_t)(i + 3) * DOUT + f];
    }
    for (; i < i1; i++) a0 += h[(size_t)i * DOUT + f];
    partial[(size_t)(g * POOL_P + p) * DOUT + f] = (a0 + a1) + (a2 + a3);
}

// Stage B: grid NG, 128 thr: reduce POOL_P partials, divide by count.
__global__ void k_pool_fin(const float* __restrict__ partial, const int* __restrict__ gstart,
                           float* __restrict__ out) {
    const int g = blockIdx.x;
    const int f = threadIdx.x;
    float acc = 0.f;
#pragma unroll
    for (int p = 0; p < POOL_P; p++) acc += partial[(size_t)(g * POOL_P + p) * DOUT + f];
    const float cnt = (float)(gstart[g + 1] - gstart[g]);
    out[(size_t)g * DOUT + f] = acc / fmaxf(cnt, 1.0f);
}

// ---------------------------------------------------------------------------
extern "C" void kernel_launch(void* const* d_in, const int* in_sizes, int n_in,
                              void* d_out, int out_size, void* d_ws, size_t ws_size,
                              hipStream_t stream) {
    const float* x = (const float*)d_in[0];
    const int* ei = (const int*)d_in[1];
    const int* batch = (const int*)d_in[2];
    const float* b1 = (const float*)d_in[4];
    const float* b2 = (const float*)d_in[6];
    const float* b3 = (const float*)d_in[8];
    const float* b4 = (const float*)d_in[10];
    const float* b5 = (const float*)d_in[12];
    const int* src = ei;
    const int* dst = ei + NE;

    char* ws = (char*)d_ws;
    size_t off = 0;
    auto alloc = [&](size_t bytes) -> char* {
        char* p = ws + off;
        off = (off + bytes + 255) & ~(size_t)255;
        return p;
    };
    float* dinv = (float*)alloc(NN * 4);
    int* cnt    = (int*)alloc(NN * 4);
    int* rp     = (int*)alloc((NN + 1) * 4);
    int* fill   = (int*)alloc(NN * 4);
    int* es     = (int*)alloc(NE * 4);
    float* ewn  = (float*)alloc(NE * 4);
    int* gstart = (int*)alloc((NG + 1) * 4);
    float* ppart = (float*)alloc((size_t)NG * POOL_P * DOUT * 4);
    ushort_t* wth = (ushort_t*)alloc(917504 * 2);
    ushort_t* wtl = (ushort_t*)alloc(917504 * 2);
    ushort_t* Xh = (ushort_t*)alloc((size_t)NN * DHID * 2);
    ushort_t* Xl = (ushort_t*)alloc((size_t)NN * DHID * 2);
    ushort_t* Yh = (ushort_t*)alloc((size_t)NN * DHID * 2);
    ushort_t* Yl = (ushort_t*)alloc((size_t)NN * DHID * 2);
    float* hF = (float*)alloc((size_t)NN * DHID * 4);  // fp32 GEMM out
    float* hOut = (float*)Xh;  // fp32 final activations (X dead by L5)
    (void)ws_size; (void)n_in; (void)in_sizes;

    hipMemsetAsync(cnt, 0, NN * 4, stream);
    hipMemsetAsync(fill, 0, NN * 4, stream);

    // CSR + norm build
    k_edges_count<<<(NE + 255) / 256, 256, 0, stream>>>(dst, cnt, NE);
    k_dinv<<<(NN + 255) / 256, 256, 0, stream>>>(cnt, dinv, NN);
    k_scan2<<<1, 1024, 0, stream>>>(cnt, rp);
    k_scatter<<<(NE + 255) / 256, 256, 0, stream>>>(src, dst, dinv, rp, fill, es, ewn, NE);
    k_gbounds<<<1, 128, 0, stream>>>(batch, gstart);

    // Weight transpose+split
    k_split_w<<<(917504 + 255) / 256, 256, 0, stream>>>(
        (const float*)d_in[3], (const float*)d_in[5], (const float*)d_in[7],
        (const float*)d_in[9], (const float*)d_in[11], wth, wtl);

    const int gy = (NN + 127) / 128;  // 79
    const ushort_t *w1h = wth, *w1l = wtl;
    const ushort_t *w2h = wth + 65536, *w2l = wtl + 65536;
    const ushort_t *w3h = wth + 327680, *w3l = wtl + 327680;
    const ushort_t *w4h = wth + 589824, *w4l = wtl + 589824;
    const ushort_t *w5h = wth + 851968, *w5l = wtl + 851968;

    // L1: agg(x, 128-dim) -> pair X ; GEMM1(+b1+relu) -> pair Y
    k_agg<DIN, 64, 1><<<NN, 64, 0, stream>>>(x, dinv, rp, es, ewn, nullptr,
                                             nullptr, Xh, Xl);
    k_mgemm<2><<<dim3(4, gy), 256, 0, stream>>>(Xh, Xl, w1h, w1l, b1, Yh, Yl, nullptr,
                                                NN, DHID, DIN);

    // L2-4: GEMM (fp32 out) -> hF ; agg(fp32 gather, +bias+relu, pair out) -> Y
    k_mgemm<0><<<dim3(4, gy), 256, 0, stream>>>(Yh, Yl, w2h, w2l, nullptr, nullptr, nullptr, hF,
                                                NN, DHID, DHID);
    k_agg<DHID, 128, 2><<<NN, 128, 0, stream>>>(hF, dinv, rp, es, ewn, b2, nullptr, Yh, Yl);
    k_mgemm<0><<<dim3(4, gy), 256, 0, stream>>>(Yh, Yl, w3h, w3l, nullptr, nullptr, nullptr, hF,
                                                NN, DHID, DHID);
    k_agg<DHID, 128, 2><<<NN, 128, 0, stream>>>(hF, dinv, rp, es, ewn, b3, nullptr, Yh, Yl);
    k_mgemm<0><<<dim3(4, gy), 256, 0, stream>>>(Yh, Yl, w4h, w4l, nullptr, nullptr, nullptr, hF,
                                                NN, DHID, DHID);
    k_agg<DHID, 128, 2><<<NN, 128, 0, stream>>>(hF, dinv, rp, es, ewn, b4, nullptr, Yh, Yl);

    // L5: GEMM (512->128, fp32 out) -> hF ; agg(+b5+relu, fp32 out) -> hOut
    k_mgemm<0><<<dim3(1, gy), 256, 0, stream>>>(Yh, Yl, w5h, w5l, nullptr, nullptr, nullptr, hF,
                                                NN, DOUT, DHID);
    k_agg<DOUT, 64, 0><<<NN, 64, 0, stream>>>(hF, dinv, rp, es, ewn, b5, hOut, nullptr, nullptr);

    // Mean pool: two-stage deterministic partition reduce
    k_pool_part<<<dim3(NG, POOL_P), DOUT, 0, stream>>>(hOut, gstart, ppart);
    k_pool_fin<<<NG, DOUT, 0, stream>>>(ppart, gstart, (float*)d_out);
}

// Round 8
// 415.377 us; speedup vs baseline: 1.7011x; 1.0033x over previous
//
#include <hip/hip_runtime.h>
#include <stdint.h>

#define NN 10000
#define NE 150000
#define NG 64
#define DIN 128
#define DHID 512
#define DOUT 128
#define POOL_P 16  // pool partitions per graph

typedef float f32x4 __attribute__((ext_vector_type(4)));
typedef short s16x8 __attribute__((ext_vector_type(8)));
typedef unsigned short us4 __attribute__((ext_vector_type(4)));
typedef unsigned short us2 __attribute__((ext_vector_type(2)));
typedef unsigned short ushort_t;

// ---------------------------------------------------------------------------
// bf16 helpers (RNE)
// ---------------------------------------------------------------------------
__device__ __forceinline__ ushort_t f2bf(float f) {
    unsigned u = __float_as_uint(f);
    u += 0x7FFFu + ((u >> 16) & 1u);
    return (ushort_t)(u >> 16);
}
__device__ __forceinline__ float bf2f(ushort_t s) {
    return __uint_as_float(((unsigned)s) << 16);
}

__device__ __forceinline__ void gl_lds16(const void* g, void* l) {
    __builtin_amdgcn_global_load_lds(
        (const __attribute__((address_space(1))) unsigned int*)g,
        (__attribute__((address_space(3))) unsigned int*)l, 16, 0, 0);
}

__device__ __forceinline__ void mfma_bf16(f32x4& d, s16x8 a, s16x8 b) {
    asm("v_mfma_f32_16x16x32_bf16 %0, %1, %2, %0" : "+v"(d) : "v"(a), "v"(b));
}

// ---------------------------------------------------------------------------
// CSR build
// ---------------------------------------------------------------------------
__global__ void k_edges_count(const int* __restrict__ dst, int* __restrict__ cnt, int E) {
    int e = blockIdx.x * blockDim.x + threadIdx.x;
    if (e < E) atomicAdd(&cnt[dst[e]], 1);
}

__global__ void k_dinv(const int* __restrict__ cnt, float* __restrict__ dinv, int n) {
    int i = blockIdx.x * blockDim.x + threadIdx.x;
    if (i < n) dinv[i] = rsqrtf(1.0f + (float)cnt[i]);  // +1 self loop
}

// 1024-thread single-block exclusive scan of cnt[0..NN) -> rp[0..NN]
__global__ void k_scan2(const int* __restrict__ cnt, int* __restrict__ rp) {
    const int C = 10;  // 1024*10 >= 10001
    const int t = threadIdx.x;
    const int lane = t & 63, w = t >> 6;
    const int base = t * C;
    int v[C];
    int s = 0;
#pragma unroll
    for (int j = 0; j < C; j++) {
        int i = base + j;
        v[j] = (i < NN) ? cnt[i] : 0;
        s += v[j];
    }
    int sc = s;
#pragma unroll
    for (int off = 1; off < 64; off <<= 1) {
        int tv = __shfl_up(sc, off);
        if (lane >= off) sc += tv;
    }
    __shared__ int wsum[16], woff[16];
    if (lane == 63) wsum[w] = sc;
    __syncthreads();
    if (t == 0) {
        int c = 0;
#pragma unroll
        for (int k = 0; k < 16; k++) { woff[k] = c; c += wsum[k]; }
    }
    __syncthreads();
    int pre = woff[w] + (sc - s);
#pragma unroll
    for (int j = 0; j < C; j++) {
        int i = base + j;
        if (i <= NN) rp[i] = pre;
        pre += v[j];
    }
}

__global__ void k_scatter(const int* __restrict__ src, const int* __restrict__ dst,
                          const float* __restrict__ dinv, const int* __restrict__ rp,
                          int* __restrict__ fill, int* __restrict__ es,
                          float* __restrict__ ew, int E) {
    int e = blockIdx.x * blockDim.x + threadIdx.x;
    if (e < E) {
        int d = dst[e], s = src[e];
        int p = rp[d] + atomicAdd(&fill[d], 1);
        es[p] = s;
        ew[p] = dinv[s] * dinv[d];
    }
}

// ---------------------------------------------------------------------------
// Weight transpose + bf16 hi/lo split (all 5 layers, one launch)
// ---------------------------------------------------------------------------
__global__ void k_split_w(const float* __restrict__ W1, const float* __restrict__ W2,
                          const float* __restrict__ W3, const float* __restrict__ W4,
                          const float* __restrict__ W5,
                          ushort_t* __restrict__ th, ushort_t* __restrict__ tl) {
    int t = blockIdx.x * blockDim.x + threadIdx.x;
    const float* W;
    int K, Mw, off, r;
    if (t < 65536)       { W = W1; K = 128; Mw = 512; off = 0;      r = t; }
    else if (t < 327680) { W = W2; K = 512; Mw = 512; off = 65536;  r = t - 65536; }
    else if (t < 589824) { W = W3; K = 512; Mw = 512; off = 327680; r = t - 327680; }
    else if (t < 851968) { W = W4; K = 512; Mw = 512; off = 589824; r = t - 589824; }
    else if (t < 917504) { W = W5; K = 512; Mw = 128; off = 851968; r = t - 851968; }
    else return;
    const int k = r / Mw, m = r % Mw;
    const float f = W[r];
    const ushort_t h = f2bf(f);
    const ushort_t l = f2bf(f - bf2f(h));
    const int o = off + m * K + k;
    th[o] = h;
    tl[o] = l;
}

// ---------------------------------------------------------------------------
// bf16x3 split MFMA GEMM: C[M][N] = (Ah+Al)[M][K] @ (Bh+Bl)^T  (Bt is [N][K])
// 128x128 tile, BK=32, 4 waves (2x2 of 64x64), 16x16x32 MFMA.
// LDS double-buffered: prefetch k-step t+1 while computing t (one barrier/iter).
// EPI: 0 = fp32 C out; 2 = bias+relu+split-pair out.
// ---------------------------------------------------------------------------
template <int EPI>
__global__ __launch_bounds__(256, 2) void k_mgemm(
    const ushort_t* __restrict__ Ah, const ushort_t* __restrict__ Al,
    const ushort_t* __restrict__ Bh, const ushort_t* __restrict__ Bl,
    const float* __restrict__ bias,
    ushort_t* __restrict__ Ch, ushort_t* __restrict__ Cl, float* __restrict__ Cf,
    const int M, const int N, const int K) {
    __shared__ ushort_t sAh[2][128 * 32], sAl[2][128 * 32];
    __shared__ ushort_t sBh[2][128 * 32], sBl[2][128 * 32];
    const int tid = threadIdx.x;
    const int lane = tid & 63, wv = tid >> 6;
    const int ln = lane & 15, lhi = lane >> 4;
    const int kg = lhi * 8;
    const int wr = (wv >> 1) * 64, wc = (wv & 1) * 64;
    const int row0 = blockIdx.y * 128, col0 = blockIdx.x * 128;
    const int sr = tid >> 2;
    const int sk = (tid & 3) * 8;

    auto STAGE = [&](int buf, int k0) {
        const int koff = k0 + sk;
        int ra0 = row0 + sr;      if (ra0 > M - 1) ra0 = M - 1;
        int ra1 = row0 + 64 + sr; if (ra1 > M - 1) ra1 = M - 1;
        gl_lds16(&Ah[(size_t)ra0 * K + koff], &sAh[buf][sr * 32 + sk]);
        gl_lds16(&Ah[(size_t)ra1 * K + koff], &sAh[buf][(64 + sr) * 32 + sk]);
        gl_lds16(&Al[(size_t)ra0 * K + koff], &sAl[buf][sr * 32 + sk]);
        gl_lds16(&Al[(size_t)ra1 * K + koff], &sAl[buf][(64 + sr) * 32 + sk]);
        const size_t cb0 = (size_t)(col0 + sr) * K + koff;
        const size_t cb1 = (size_t)(col0 + 64 + sr) * K + koff;
        gl_lds16(&Bh[cb0], &sBh[buf][sr * 32 + sk]);
        gl_lds16(&Bh[cb1], &sBh[buf][(64 + sr) * 32 + sk]);
        gl_lds16(&Bl[cb0], &sBl[buf][sr * 32 + sk]);
        gl_lds16(&Bl[cb1], &sBl[buf][(64 + sr) * 32 + sk]);
    };

    f32x4 acc[4][4] = {};

    STAGE(0, 0);
    __syncthreads();  // drain prologue staging

    const int nk = K / 32;
    for (int t = 0; t < nk; t++) {
        const int cur = t & 1;
        if (t + 1 < nk) STAGE(cur ^ 1, (t + 1) * 32);  // async prefetch

        s16x8 a_h[4], a_l[4], b_h[4], b_l[4];
#pragma unroll
        for (int m = 0; m < 4; m++) {
            const int r = (wr + m * 16 + ln) * 32 + kg;
            a_h[m] = *reinterpret_cast<const s16x8*>(&sAh[cur][r]);
            a_l[m] = *reinterpret_cast<const s16x8*>(&sAl[cur][r]);
        }
#pragma unroll
        for (int n = 0; n < 4; n++) {
            const int c = (wc + n * 16 + ln) * 32 + kg;
            b_h[n] = *reinterpret_cast<const s16x8*>(&sBh[cur][c]);
            b_l[n] = *reinterpret_cast<const s16x8*>(&sBl[cur][c]);
        }
#pragma unroll
        for (int m = 0; m < 4; m++)
#pragma unroll
            for (int n = 0; n < 4; n++) {
                mfma_bf16(acc[m][n], a_h[m], b_h[n]);
                mfma_bf16(acc[m][n], a_h[m], b_l[n]);
                mfma_bf16(acc[m][n], a_l[m], b_h[n]);
            }
        __syncthreads();  // drains prefetch vmcnt + this iter's lgkm
    }

    asm volatile("s_nop 7\n\ts_nop 7");  // MFMA->VALU hazard guard

#pragma unroll
    for (int n = 0; n < 4; n++) {
        const int col = col0 + wc + n * 16 + ln;
        const float bv = (EPI == 2) ? bias[col] : 0.0f;
#pragma unroll
        for (int m = 0; m < 4; m++) {
#pragma unroll
            for (int j = 0; j < 4; j++) {
                const int row = row0 + wr + m * 16 + lhi * 4 + j;
                if (row < M) {
                    float f = acc[m][n][j];
                    const size_t o = (size_t)row * N + col;
                    if constexpr (EPI == 2) {
                        f = fmaxf(f + bv, 0.0f);
                        const ushort_t h = f2bf(f);
                        Ch[o] = h;
                        Cl[o] = f2bf(f - bf2f(h));
                    } else {
                        Cf[o] = f;
                    }
                }
            }
        }
    }
}

// ---------------------------------------------------------------------------
// Aggregation over fp32 input, edge loop unrolled x4 with 4 partial
// accumulator sets (4 independent gathers in flight per wave).
// OUTM: 0 = fp32 out +bias+relu; 1 = split-pair plain; 2 = split +bias+relu.
// ---------------------------------------------------------------------------
template <int M_, int TPB, int OUTM>
__global__ void k_agg(const float* __restrict__ xf, const float* __restrict__ dinv,
                      const int* __restrict__ rp, const int* __restrict__ es,
                      const float* __restrict__ ew, const float* __restrict__ bias,
                      float* __restrict__ of, ushort_t* __restrict__ oh,
                      ushort_t* __restrict__ ol) {
    constexpr int VEC = M_ / TPB;
    static_assert(VEC == 2 || VEC == 4, "");
    const int node = blockIdx.x;
    const int tid = threadIdx.x;
    __shared__ int s_src[64];
    __shared__ float s_w[64];

    const float di = dinv[node];
    const float sw = di * di;
    const size_t selfo = (size_t)node * M_ + tid * VEC;
    float a0[VEC], a1[VEC] = {}, a2[VEC] = {}, a3[VEC] = {};
    if constexpr (VEC == 4) {
        float4 v = *reinterpret_cast<const float4*>(&xf[selfo]);
        a0[0] = v.x * sw; a0[1] = v.y * sw; a0[2] = v.z * sw; a0[3] = v.w * sw;
    } else {
        float2 v = *reinterpret_cast<const float2*>(&xf[selfo]);
        a0[0] = v.x * sw; a0[1] = v.y * sw;
    }

    const int beg = rp[node], end = rp[node + 1];
    for (int c = beg; c < end; c += 64) {
        const int m = min(64, end - c);
        __syncthreads();
        if (tid < m) { s_src[tid] = es[c + tid]; s_w[tid] = ew[c + tid]; }
        __syncthreads();
        int e = 0;
        for (; e + 3 < m; e += 4) {
            const float w0 = s_w[e], w1 = s_w[e + 1], w2 = s_w[e + 2], w3 = s_w[e + 3];
            const size_t o0 = (size_t)s_src[e] * M_ + tid * VEC;
            const size_t o1 = (size_t)s_src[e + 1] * M_ + tid * VEC;
            const size_t o2 = (size_t)s_src[e + 2] * M_ + tid * VEC;
            const size_t o3 = (size_t)s_src[e + 3] * M_ + tid * VEC;
            if constexpr (VEC == 4) {
                float4 v0 = *reinterpret_cast<const float4*>(&xf[o0]);
                float4 v1 = *reinterpret_cast<const float4*>(&xf[o1]);
                float4 v2 = *reinterpret_cast<const float4*>(&xf[o2]);
                float4 v3 = *reinterpret_cast<const float4*>(&xf[o3]);
                a0[0] = fmaf(v0.x, w0, a0[0]); a0[1] = fmaf(v0.y, w0, a0[1]);
                a0[2] = fmaf(v0.z, w0, a0[2]); a0[3] = fmaf(v0.w, w0, a0[3]);
                a1[0] = fmaf(v1.x, w1, a1[0]); a1[1] = fmaf(v1.y, w1, a1[1]);
                a1[2] = fmaf(v1.z, w1, a1[2]); a1[3] = fmaf(v1.w, w1, a1[3]);
                a2[0] = fmaf(v2.x, w2, a2[0]); a2[1] = fmaf(v2.y, w2, a2[1]);
                a2[2] = fmaf(v2.z, w2, a2[2]); a2[3] = fmaf(v2.w, w2, a2[3]);
                a3[0] = fmaf(v3.x, w3, a3[0]); a3[1] = fmaf(v3.y, w3, a3[1]);
                a3[2] = fmaf(v3.z, w3, a3[2]); a3[3] = fmaf(v3.w, w3, a3[3]);
            } else {
                float2 v0 = *reinterpret_cast<const float2*>(&xf[o0]);
                float2 v1 = *reinterpret_cast<const float2*>(&xf[o1]);
                float2 v2 = *reinterpret_cast<const float2*>(&xf[o2]);
                float2 v3 = *reinterpret_cast<const float2*>(&xf[o3]);
                a0[0] = fmaf(v0.x, w0, a0[0]); a0[1] = fmaf(v0.y, w0, a0[1]);
                a1[0] = fmaf(v1.x, w1, a1[0]); a1[1] = fmaf(v1.y, w1, a1[1]);
                a2[0] = fmaf(v2.x, w2, a2[0]); a2[1] = fmaf(v2.y, w2, a2[1]);
                a3[0] = fmaf(v3.x, w3, a3[0]); a3[1] = fmaf(v3.y, w3, a3[1]);
            }
        }
        for (; e < m; e++) {
            const float w = s_w[e];
            const size_t o = (size_t)s_src[e] * M_ + tid * VEC;
            if constexpr (VEC == 4) {
                float4 v = *reinterpret_cast<const float4*>(&xf[o]);
                a0[0] = fmaf(v.x, w, a0[0]); a0[1] = fmaf(v.y, w, a0[1]);
                a0[2] = fmaf(v.z, w, a0[2]); a0[3] = fmaf(v.w, w, a0[3]);
            } else {
                float2 v = *reinterpret_cast<const float2*>(&xf[o]);
                a0[0] = fmaf(v.x, w, a0[0]); a0[1] = fmaf(v.y, w, a0[1]);
            }
        }
    }

    float accv[VEC];
#pragma unroll
    for (int j = 0; j < VEC; j++) {
        float f = (a0[j] + a1[j]) + (a2[j] + a3[j]);
        if constexpr (OUTM != 1) f = fmaxf(f + bias[tid * VEC + j], 0.0f);
        accv[j] = f;
    }
    if constexpr (OUTM == 0) {
        if constexpr (VEC == 4)
            *reinterpret_cast<float4*>(&of[selfo]) = make_float4(accv[0], accv[1], accv[2], accv[3]);
        else
            *reinterpret_cast<float2*>(&of[selfo]) = make_float2(accv[0], accv[1]);
    } else {
        ushort_t hh[VEC], ll[VEC];
#pragma unroll
        for (int j = 0; j < VEC; j++) {
            hh[j] = f2bf(accv[j]);
            ll[j] = f2bf(accv[j] - bf2f(hh[j]));
        }
        if constexpr (VEC == 4) {
            us4 h4 = {hh[0], hh[1], hh[2], hh[3]}, l4 = {ll[0], ll[1], ll[2], ll[3]};
            *reinterpret_cast<us4*>(&oh[selfo]) = h4;
            *reinterpret_cast<us4*>(&ol[selfo]) = l4;
        } else {
            us2 h2 = {hh[0], hh[1]}, l2 = {ll[0], ll[1]};
            *reinterpret_cast<us2*>(&oh[selfo]) = h2;
            *reinterpret_cast<us2*>(&ol[selfo]) = l2;
        }
    }
}

// ---------------------------------------------------------------------------
// Mean pool: batch is SORTED -> per-graph contiguous ranges, no atomics.
// Two-stage partition reduce for occupancy.
// ---------------------------------------------------------------------------
__global__ void k_gbounds(const int* __restrict__ batch, int* __restrict__ gstart) {
    const int g = threadIdx.x;  // 0..64
    if (g > NG) return;
    int lo = 0, hi = NN;  // first index with batch[i] >= g
    while (lo < hi) {
        int mid = (lo + hi) >> 1;
        if (batch[mid] < g) lo = mid + 1; else hi = mid;
    }
    gstart[g] = lo;
}

// Stage A: grid (NG, POOL_P), 128 thr. partial[(g*POOL_P+p)*DOUT + f]
__global__ void k_pool_part(const float* __restrict__ h, const int* __restrict__ gstart,
                            float* __restrict__ partial) {
    const int g = blockIdx.x, p = blockIdx.y;
    const int f = threadIdx.x;  // 128
    const int s = gstart[g], e = gstart[g + 1];
    const int len = e - s;
    const int chunk = (len + POOL_P - 1) / POOL_P;
    const int i0 = s + p * chunk;
    const int i1 = min(i0 + chunk, e);
    float a0 = 0.f, a1 = 0.f, a2 = 0.f, a3 = 0.f;
    int i = i0;
    for (; i + 3 < i1; i += 4) {
        a0 += h[(size_t)(i + 0) * DOUT + f];
        a1 += h[(size_t)(i + 1) * DOUT + f];
        a2 += h[(size_t)(i + 2) * DOUT + f];
        a3 += h[(size_t)(i + 3) * DOUT + f];
    }
    for (; i < i1; i++) a0 += h[(size_t)i * DOUT + f];
    partial[(size_t)(g * POOL_P + p) * DOUT + f] = (a0 + a1) + (a2 + a3);
}

// Stage B: grid NG, 128 thr: reduce POOL_P partials, divide by count.
__global__ void k_pool_fin(const float* __restrict__ partial, const int* __restrict__ gstart,
                           float* __restrict__ out) {
    const int g = blockIdx.x;
    const int f = threadIdx.x;
    float acc = 0.f;
#pragma unroll
    for (int p = 0; p < POOL_P; p++) acc += partial[(size_t)(g * POOL_P + p) * DOUT + f];
    const float cnt = (float)(gstart[g + 1] - gstart[g]);
    out[(size_t)g * DOUT + f] = acc / fmaxf(cnt, 1.0f);
}

// ---------------------------------------------------------------------------
extern "C" void kernel_launch(void* const* d_in, const int* in_sizes, int n_in,
                              void* d_out, int out_size, void* d_ws, size_t ws_size,
                              hipStream_t stream) {
    const float* x = (const float*)d_in[0];
    const int* ei = (const int*)d_in[1];
    const int* batch = (const int*)d_in[2];
    const float* b1 = (const float*)d_in[4];
    const float* b2 = (const float*)d_in[6];
    const float* b3 = (const float*)d_in[8];
    const float* b4 = (const float*)d_in[10];
    const float* b5 = (const float*)d_in[12];
    const int* src = ei;
    const int* dst = ei + NE;

    char* ws = (char*)d_ws;
    size_t off = 0;
    auto alloc = [&](size_t bytes) -> char* {
        char* p = ws + off;
        off = (off + bytes + 255) & ~(size_t)255;
        return p;
    };
    float* dinv = (float*)alloc(NN * 4);
    int* cnt    = (int*)alloc(NN * 4);
    int* rp     = (int*)alloc((NN + 1) * 4);
    int* fill   = (int*)alloc(NN * 4);
    int* es     = (int*)alloc(NE * 4);
    float* ewn  = (float*)alloc(NE * 4);
    int* gstart = (int*)alloc((NG + 1) * 4);
    float* ppart = (float*)alloc((size_t)NG * POOL_P * DOUT * 4);
    ushort_t* wth = (ushort_t*)alloc(917504 * 2);
    ushort_t* wtl = (ushort_t*)alloc(917504 * 2);
    ushort_t* Xh = (ushort_t*)alloc((size_t)NN * DHID * 2);
    ushort_t* Xl = (ushort_t*)alloc((size_t)NN * DHID * 2);
    ushort_t* Yh = (ushort_t*)alloc((size_t)NN * DHID * 2);
    ushort_t* Yl = (ushort_t*)alloc((size_t)NN * DHID * 2);
    float* hF = (float*)alloc((size_t)NN * DHID * 4);  // fp32 GEMM out
    float* hOut = (float*)Xh;  // fp32 final activations (X dead by L5)
    (void)ws_size; (void)n_in; (void)in_sizes;

    hipMemsetAsync(cnt, 0, NN * 4, stream);
    hipMemsetAsync(fill, 0, NN * 4, stream);

    // CSR + norm build
    k_edges_count<<<(NE + 255) / 256, 256, 0, stream>>>(dst, cnt, NE);
    k_dinv<<<(NN + 255) / 256, 256, 0, stream>>>(cnt, dinv, NN);
    k_scan2<<<1, 1024, 0, stream>>>(cnt, rp);
    k_scatter<<<(NE + 255) / 256, 256, 0, stream>>>(src, dst, dinv, rp, fill, es, ewn, NE);
    k_gbounds<<<1, 128, 0, stream>>>(batch, gstart);

    // Weight transpose+split
    k_split_w<<<(917504 + 255) / 256, 256, 0, stream>>>(
        (const float*)d_in[3], (const float*)d_in[5], (const float*)d_in[7],
        (const float*)d_in[9], (const float*)d_in[11], wth, wtl);

    const int gy = (NN + 127) / 128;  // 79
    const ushort_t *w1h = wth, *w1l = wtl;
    const ushort_t *w2h = wth + 65536, *w2l = wtl + 65536;
    const ushort_t *w3h = wth + 327680, *w3l = wtl + 327680;
    const ushort_t *w4h = wth + 589824, *w4l = wtl + 589824;
    const ushort_t *w5h = wth + 851968, *w5l = wtl + 851968;

    // L1: agg(x, 128-dim) -> pair X ; GEMM1(+b1+relu) -> pair Y
    k_agg<DIN, 64, 1><<<NN, 64, 0, stream>>>(x, dinv, rp, es, ewn, nullptr,
                                             nullptr, Xh, Xl);
    k_mgemm<2><<<dim3(4, gy), 256, 0, stream>>>(Xh, Xl, w1h, w1l, b1, Yh, Yl, nullptr,
                                                NN, DHID, DIN);

    // L2-4: GEMM (fp32 out) -> hF ; agg(fp32 gather, +bias+relu, pair out) -> Y
    k_mgemm<0><<<dim3(4, gy), 256, 0, stream>>>(Yh, Yl, w2h, w2l, nullptr, nullptr, nullptr, hF,
                                                NN, DHID, DHID);
    k_agg<DHID, 128, 2><<<NN, 128, 0, stream>>>(hF, dinv, rp, es, ewn, b2, nullptr, Yh, Yl);
    k_mgemm<0><<<dim3(4, gy), 256, 0, stream>>>(Yh, Yl, w3h, w3l, nullptr, nullptr, nullptr, hF,
                                                NN, DHID, DHID);
    k_agg<DHID, 128, 2><<<NN, 128, 0, stream>>>(hF, dinv, rp, es, ewn, b3, nullptr, Yh, Yl);
    k_mgemm<0><<<dim3(4, gy), 256, 0, stream>>>(Yh, Yl, w4h, w4l, nullptr, nullptr, nullptr, hF,
                                                NN, DHID, DHID);
    k_agg<DHID, 128, 2><<<NN, 128, 0, stream>>>(hF, dinv, rp, es, ewn, b4, nullptr, Yh, Yl);

    // L5: GEMM (512->128, fp32 out) -> hF ; agg(+b5+relu, fp32 out) -> hOut
    k_mgemm<0><<<dim3(1, gy), 256, 0, stream>>>(Yh, Yl, w5h, w5l, nullptr, nullptr, nullptr, hF,
                                                NN, DOUT, DHID);
    k_agg<DOUT, 64, 0><<<NN, 64, 0, stream>>>(hF, dinv, rp, es, ewn, b5, hOut, nullptr, nullptr);

    // Mean pool: two-stage deterministic partition reduce
    k_pool_part<<<dim3(NG, POOL_P), DOUT, 0, stream>>>(hOut, gstart, ppart);
    k_pool_fin<<<NG, DOUT, 0, stream>>>(ppart, gstart, (float*)d_out);
}

// Round 10
// 379.690 us; speedup vs baseline: 1.8610x; 1.0940x over previous
//
#include <hip/hip_runtime.h>
#include <stdint.h>

#define NN 10000
#define NE 150000
#define NG 64
#define DIN 128
#define DHID 512
#define DOUT 128
#define POOL_P 16  // pool partitions per graph

typedef float f32x4 __attribute__((ext_vector_type(4)));
typedef short s16x8 __attribute__((ext_vector_type(8)));
typedef unsigned short us4 __attribute__((ext_vector_type(4)));
typedef unsigned short us2 __attribute__((ext_vector_type(2)));
typedef unsigned short ushort_t;

// ---------------------------------------------------------------------------
// bf16 helpers (RNE)
// ---------------------------------------------------------------------------
__device__ __forceinline__ ushort_t f2bf(float f) {
    unsigned u = __float_as_uint(f);
    u += 0x7FFFu + ((u >> 16) & 1u);
    return (ushort_t)(u >> 16);
}
__device__ __forceinline__ float bf2f(ushort_t s) {
    return __uint_as_float(((unsigned)s) << 16);
}

__device__ __forceinline__ void gl_lds16(const void* g, void* l) {
    __builtin_amdgcn_global_load_lds(
        (const __attribute__((address_space(1))) unsigned int*)g,
        (__attribute__((address_space(3))) unsigned int*)l, 16, 0, 0);
}

__device__ __forceinline__ void mfma_bf16(f32x4& d, s16x8 a, s16x8 b) {
    asm("v_mfma_f32_16x16x32_bf16 %0, %1, %2, %0" : "+v"(d) : "v"(a), "v"(b));
}

// ---------------------------------------------------------------------------
// CSR build
// ---------------------------------------------------------------------------
__global__ void k_edges_count(const int* __restrict__ dst, int* __restrict__ cnt, int E) {
    int e = blockIdx.x * blockDim.x + threadIdx.x;
    if (e < E) atomicAdd(&cnt[dst[e]], 1);
}

__global__ void k_dinv(const int* __restrict__ cnt, float* __restrict__ dinv, int n) {
    int i = blockIdx.x * blockDim.x + threadIdx.x;
    if (i < n) dinv[i] = rsqrtf(1.0f + (float)cnt[i]);  // +1 self loop
}

// 1024-thread single-block exclusive scan of cnt[0..NN) -> rp[0..NN]
__global__ void k_scan2(const int* __restrict__ cnt, int* __restrict__ rp) {
    const int C = 10;  // 1024*10 >= 10001
    const int t = threadIdx.x;
    const int lane = t & 63, w = t >> 6;
    const int base = t * C;
    int v[C];
    int s = 0;
#pragma unroll
    for (int j = 0; j < C; j++) {
        int i = base + j;
        v[j] = (i < NN) ? cnt[i] : 0;
        s += v[j];
    }
    int sc = s;
#pragma unroll
    for (int off = 1; off < 64; off <<= 1) {
        int tv = __shfl_up(sc, off);
        if (lane >= off) sc += tv;
    }
    __shared__ int wsum[16], woff[16];
    if (lane == 63) wsum[w] = sc;
    __syncthreads();
    if (t == 0) {
        int c = 0;
#pragma unroll
        for (int k = 0; k < 16; k++) { woff[k] = c; c += wsum[k]; }
    }
    __syncthreads();
    int pre = woff[w] + (sc - s);
#pragma unroll
    for (int j = 0; j < C; j++) {
        int i = base + j;
        if (i <= NN) rp[i] = pre;
        pre += v[j];
    }
}

__global__ void k_scatter(const int* __restrict__ src, const int* __restrict__ dst,
                          const float* __restrict__ dinv, const int* __restrict__ rp,
                          int* __restrict__ fill, int* __restrict__ es,
                          float* __restrict__ ew, int E) {
    int e = blockIdx.x * blockDim.x + threadIdx.x;
    if (e < E) {
        int d = dst[e], s = src[e];
        int p = rp[d] + atomicAdd(&fill[d], 1);
        es[p] = s;
        ew[p] = dinv[s] * dinv[d];
    }
}

// ---------------------------------------------------------------------------
// Weight transpose + bf16 hi/lo split (all 5 layers, one launch)
// ---------------------------------------------------------------------------
__global__ void k_split_w(const float* __restrict__ W1, const float* __restrict__ W2,
                          const float* __restrict__ W3, const float* __restrict__ W4,
                          const float* __restrict__ W5,
                          ushort_t* __restrict__ th, ushort_t* __restrict__ tl) {
    int t = blockIdx.x * blockDim.x + threadIdx.x;
    const float* W;
    int K, Mw, off, r;
    if (t < 65536)       { W = W1; K = 128; Mw = 512; off = 0;      r = t; }
    else if (t < 327680) { W = W2; K = 512; Mw = 512; off = 65536;  r = t - 65536; }
    else if (t < 589824) { W = W3; K = 512; Mw = 512; off = 327680; r = t - 327680; }
    else if (t < 851968) { W = W4; K = 512; Mw = 512; off = 589824; r = t - 589824; }
    else if (t < 917504) { W = W5; K = 512; Mw = 128; off = 851968; r = t - 851968; }
    else return;
    const int k = r / Mw, m = r % Mw;
    const float f = W[r];
    const ushort_t h = f2bf(f);
    const ushort_t l = f2bf(f - bf2f(h));
    const int o = off + m * K + k;
    th[o] = h;
    tl[o] = l;
}

// ---------------------------------------------------------------------------
// bf16x3 split MFMA GEMM: C[M][N] = (Ah+Al)[M][K] @ (Bh+Bl)^T  (Bt is [N][K])
// 128x128 tile, BK=32, 4 waves (2x2 of 64x64), 16x16x32 MFMA.
// LDS double-buffered: prefetch k-step t+1 while computing t (one barrier/iter).
// EPI: 0 = fp32 C out; 2 = bias+relu+split-pair out.
// ---------------------------------------------------------------------------
template <int EPI>
__global__ __launch_bounds__(256, 2) void k_mgemm(
    const ushort_t* __restrict__ Ah, const ushort_t* __restrict__ Al,
    const ushort_t* __restrict__ Bh, const ushort_t* __restrict__ Bl,
    const float* __restrict__ bias,
    ushort_t* __restrict__ Ch, ushort_t* __restrict__ Cl, float* __restrict__ Cf,
    const int M, const int N, const int K) {
    __shared__ ushort_t sAh[2][128 * 32], sAl[2][128 * 32];
    __shared__ ushort_t sBh[2][128 * 32], sBl[2][128 * 32];
    const int tid = threadIdx.x;
    const int lane = tid & 63, wv = tid >> 6;
    const int ln = lane & 15, lhi = lane >> 4;
    const int kg = lhi * 8;
    const int wr = (wv >> 1) * 64, wc = (wv & 1) * 64;
    const int row0 = blockIdx.y * 128, col0 = blockIdx.x * 128;
    const int sr = tid >> 2;
    const int sk = (tid & 3) * 8;

    auto STAGE = [&](int buf, int k0) {
        const int koff = k0 + sk;
        int ra0 = row0 + sr;      if (ra0 > M - 1) ra0 = M - 1;
        int ra1 = row0 + 64 + sr; if (ra1 > M - 1) ra1 = M - 1;
        gl_lds16(&Ah[(size_t)ra0 * K + koff], &sAh[buf][sr * 32 + sk]);
        gl_lds16(&Ah[(size_t)ra1 * K + koff], &sAh[buf][(64 + sr) * 32 + sk]);
        gl_lds16(&Al[(size_t)ra0 * K + koff], &sAl[buf][sr * 32 + sk]);
        gl_lds16(&Al[(size_t)ra1 * K + koff], &sAl[buf][(64 + sr) * 32 + sk]);
        const size_t cb0 = (size_t)(col0 + sr) * K + koff;
        const size_t cb1 = (size_t)(col0 + 64 + sr) * K + koff;
        gl_lds16(&Bh[cb0], &sBh[buf][sr * 32 + sk]);
        gl_lds16(&Bh[cb1], &sBh[buf][(64 + sr) * 32 + sk]);
        gl_lds16(&Bl[cb0], &sBl[buf][sr * 32 + sk]);
        gl_lds16(&Bl[cb1], &sBl[buf][(64 + sr) * 32 + sk]);
    };

    f32x4 acc[4][4] = {};

    STAGE(0, 0);
    __syncthreads();  // drain prologue staging

    const int nk = K / 32;
    for (int t = 0; t < nk; t++) {
        const int cur = t & 1;
        if (t + 1 < nk) STAGE(cur ^ 1, (t + 1) * 32);  // async prefetch

        s16x8 a_h[4], a_l[4], b_h[4], b_l[4];
#pragma unroll
        for (int m = 0; m < 4; m++) {
            const int r = (wr + m * 16 + ln) * 32 + kg;
            a_h[m] = *reinterpret_cast<const s16x8*>(&sAh[cur][r]);
            a_l[m] = *reinterpret_cast<const s16x8*>(&sAl[cur][r]);
        }
#pragma unroll
        for (int n = 0; n < 4; n++) {
            const int c = (wc + n * 16 + ln) * 32 + kg;
            b_h[n] = *reinterpret_cast<const s16x8*>(&sBh[cur][c]);
            b_l[n] = *reinterpret_cast<const s16x8*>(&sBl[cur][c]);
        }
#pragma unroll
        for (int m = 0; m < 4; m++)
#pragma unroll
            for (int n = 0; n < 4; n++) {
                mfma_bf16(acc[m][n], a_h[m], b_h[n]);
                mfma_bf16(acc[m][n], a_h[m], b_l[n]);
                mfma_bf16(acc[m][n], a_l[m], b_h[n]);
            }
        __syncthreads();  // drains prefetch vmcnt + this iter's lgkm
    }

    asm volatile("s_nop 7\n\ts_nop 7");  // MFMA->VALU hazard guard

#pragma unroll
    for (int n = 0; n < 4; n++) {
        const int col = col0 + wc + n * 16 + ln;
        const float bv = (EPI == 2) ? bias[col] : 0.0f;
#pragma unroll
        for (int m = 0; m < 4; m++) {
#pragma unroll
            for (int j = 0; j < 4; j++) {
                const int row = row0 + wr + m * 16 + lhi * 4 + j;
                if (row < M) {
                    float f = acc[m][n][j];
                    const size_t o = (size_t)row * N + col;
                    if constexpr (EPI == 2) {
                        f = fmaxf(f + bv, 0.0f);
                        const ushort_t h = f2bf(f);
                        Ch[o] = h;
                        Cl[o] = f2bf(f - bf2f(h));
                    } else {
                        Cf[o] = f;
                    }
                }
            }
        }
    }
}

// ---------------------------------------------------------------------------
// Slice-aggregation: feature dim split into NSLICE slices of 64 cols.
// Grid = NN*NSLICE, 64 threads. slice = bid & (NSLICE-1) -> with NSLICE==8
// this pins each slice to one XCD (blockIdx%8 round-robin), so the slice's
// gather working set (NN*64*4B = 2.56MB) stays resident in that XCD's 4MB L2.
// OUTM: 0 = fp32 out +bias+relu; 1 = split-pair plain; 2 = split +bias+relu.
// ---------------------------------------------------------------------------
template <int M_, int NSLICE, int OUTM>
__global__ void k_aggs(const float* __restrict__ xf, const float* __restrict__ dinv,
                       const int* __restrict__ rp, const int* __restrict__ es,
                       const float* __restrict__ ew, const float* __restrict__ bias,
                       float* __restrict__ of, ushort_t* __restrict__ oh,
                       ushort_t* __restrict__ ol) {
    constexpr int SHIFT = (NSLICE == 8) ? 3 : 1;
    const int bid = blockIdx.x;
    const int slice = bid & (NSLICE - 1);
    const int node = bid >> SHIFT;
    const int f = threadIdx.x;  // 0..63
    const int col = slice * 64 + f;
    const size_t base = (size_t)node * M_ + col;

    __shared__ int s_src[64];
    __shared__ float s_w[64];

    const float di = dinv[node];
    const float sw = di * di;
    float a0 = xf[base] * sw, a1 = 0.f, a2 = 0.f, a3 = 0.f;

    const int beg = rp[node], end = rp[node + 1];
    for (int c = beg; c < end; c += 64) {
        const int m = min(64, end - c);
        __syncthreads();
        if (f < m) { s_src[f] = es[c + f]; s_w[f] = ew[c + f]; }
        __syncthreads();
        int e = 0;
        for (; e + 3 < m; e += 4) {
            const float w0 = s_w[e], w1 = s_w[e + 1], w2 = s_w[e + 2], w3 = s_w[e + 3];
            const float v0 = xf[(size_t)s_src[e] * M_ + col];
            const float v1 = xf[(size_t)s_src[e + 1] * M_ + col];
            const float v2 = xf[(size_t)s_src[e + 2] * M_ + col];
            const float v3 = xf[(size_t)s_src[e + 3] * M_ + col];
            a0 = fmaf(v0, w0, a0); a1 = fmaf(v1, w1, a1);
            a2 = fmaf(v2, w2, a2); a3 = fmaf(v3, w3, a3);
        }
        for (; e < m; e++) a0 = fmaf(xf[(size_t)s_src[e] * M_ + col], s_w[e], a0);
    }

    float v = (a0 + a1) + (a2 + a3);
    if constexpr (OUTM != 1) v = fmaxf(v + bias[col], 0.0f);
    if constexpr (OUTM == 0) {
        of[base] = v;
    } else {
        const ushort_t h = f2bf(v);
        oh[base] = h;
        ol[base] = f2bf(v - bf2f(h));
    }
}

// ---------------------------------------------------------------------------
// Mean pool: batch is SORTED -> per-graph contiguous ranges, no atomics.
// Two-stage partition reduce for occupancy.
// ---------------------------------------------------------------------------
__global__ void k_gbounds(const int* __restrict__ batch, int* __restrict__ gstart) {
    const int g = threadIdx.x;  // 0..64
    if (g > NG) return;
    int lo = 0, hi = NN;  // first index with batch[i] >= g
    while (lo < hi) {
        int mid = (lo + hi) >> 1;
        if (batch[mid] < g) lo = mid + 1; else hi = mid;
    }
    gstart[g] = lo;
}

// Stage A: grid (NG, POOL_P), 128 thr. partial[(g*POOL_P+p)*DOUT + f]
__global__ void k_pool_part(const float* __restrict__ h, const int* __restrict__ gstart,
                            float* __restrict__ partial) {
    const int g = blockIdx.x, p = blockIdx.y;
    const int f = threadIdx.x;  // 128
    const int s = gstart[g], e = gstart[g + 1];
    const int len = e - s;
    const int chunk = (len + POOL_P - 1) / POOL_P;
    const int i0 = s + p * chunk;
    const int i1 = min(i0 + chunk, e);
    float a0 = 0.f, a1 = 0.f, a2 = 0.f, a3 = 0.f;
    int i = i0;
    for (; i + 3 < i1; i += 4) {
        a0 += h[(size_t)(i + 0) * DOUT + f];
        a1 += h[(size_t)(i + 1) * DOUT + f];
        a2 += h[(size_t)(i + 2) * DOUT + f];
        a3 += h[(size_t)(i + 3) * DOUT + f];
    }
    for (; i < i1; i++) a0 += h[(size_t)i * DOUT + f];
    partial[(size_t)(g * POOL_P + p) * DOUT + f] = (a0 + a1) + (a2 + a3);
}

// Stage B: grid NG, 128 thr: reduce POOL_P partials, divide by count.
__global__ void k_pool_fin(const float* __restrict__ partial, const int* __restrict__ gstart,
                           float* __restrict__ out) {
    const int g = blockIdx.x;
    const int f = threadIdx.x;
    float acc = 0.f;
#pragma unroll
    for (int p = 0; p < POOL_P; p++) acc += partial[(size_t)(g * POOL_P + p) * DOUT + f];
    const float cnt = (float)(gstart[g + 1] - gstart[g]);
    out[(size_t)g * DOUT + f] = acc / fmaxf(cnt, 1.0f);
}

// ---------------------------------------------------------------------------
extern "C" void kernel_launch(void* const* d_in, const int* in_sizes, int n_in,
                              void* d_out, int out_size, void* d_ws, size_t ws_size,
                              hipStream_t stream) {
    const float* x = (const float*)d_in[0];
    const int* ei = (const int*)d_in[1];
    const int* batch = (const int*)d_in[2];
    const float* b1 = (const float*)d_in[4];
    const float* b2 = (const float*)d_in[6];
    const float* b3 = (const float*)d_in[8];
    const float* b4 = (const float*)d_in[10];
    const float* b5 = (const float*)d_in[12];
    const int* src = ei;
    const int* dst = ei + NE;

    char* ws = (char*)d_ws;
    size_t off = 0;
    auto alloc = [&](size_t bytes) -> char* {
        char* p = ws + off;
        off = (off + bytes + 255) & ~(size_t)255;
        return p;
    };
    float* dinv = (float*)alloc(NN * 4);
    int* cnt    = (int*)alloc(NN * 4);
    int* rp     = (int*)alloc((NN + 1) * 4);
    int* fill   = (int*)alloc(NN * 4);
    int* es     = (int*)alloc(NE * 4);
    float* ewn  = (float*)alloc(NE * 4);
    int* gstart = (int*)alloc((NG + 1) * 4);
    float* ppart = (float*)alloc((size_t)NG * POOL_P * DOUT * 4);
    ushort_t* wth = (ushort_t*)alloc(917504 * 2);
    ushort_t* wtl = (ushort_t*)alloc(917504 * 2);
    ushort_t* Xh = (ushort_t*)alloc((size_t)NN * DHID * 2);
    ushort_t* Xl = (ushort_t*)alloc((size_t)NN * DHID * 2);
    ushort_t* Yh = (ushort_t*)alloc((size_t)NN * DHID * 2);
    ushort_t* Yl = (ushort_t*)alloc((size_t)NN * DHID * 2);
    float* hF = (float*)alloc((size_t)NN * DHID * 4);  // fp32 GEMM out
    float* hOut = (float*)Xh;  // fp32 final activations (X dead by L5)
    (void)ws_size; (void)n_in; (void)in_sizes;

    hipMemsetAsync(cnt, 0, NN * 4, stream);
    hipMemsetAsync(fill, 0, NN * 4, stream);

    // CSR + norm build
    k_edges_count<<<(NE + 255) / 256, 256, 0, stream>>>(dst, cnt, NE);
    k_dinv<<<(NN + 255) / 256, 256, 0, stream>>>(cnt, dinv, NN);
    k_scan2<<<1, 1024, 0, stream>>>(cnt, rp);
    k_scatter<<<(NE + 255) / 256, 256, 0, stream>>>(src, dst, dinv, rp, fill, es, ewn, NE);
    k_gbounds<<<1, 128, 0, stream>>>(batch, gstart);

    // Weight transpose+split
    k_split_w<<<(917504 + 255) / 256, 256, 0, stream>>>(
        (const float*)d_in[3], (const float*)d_in[5], (const float*)d_in[7],
        (const float*)d_in[9], (const float*)d_in[11], wth, wtl);

    const int gy = (NN + 127) / 128;  // 79
    const ushort_t *w1h = wth, *w1l = wtl;
    const ushort_t *w2h = wth + 65536, *w2l = wtl + 65536;
    const ushort_t *w3h = wth + 327680, *w3l = wtl + 327680;
    const ushort_t *w4h = wth + 589824, *w4l = wtl + 589824;
    const ushort_t *w5h = wth + 851968, *w5l = wtl + 851968;

    // L1: agg(x, 128-dim, 2 slices) -> pair X ; GEMM1(+b1+relu) -> pair Y
    k_aggs<DIN, 2, 1><<<NN * 2, 64, 0, stream>>>(x, dinv, rp, es, ewn, nullptr,
                                                 nullptr, Xh, Xl);
    k_mgemm<2><<<dim3(4, gy), 256, 0, stream>>>(Xh, Xl, w1h, w1l, b1, Yh, Yl, nullptr,
                                                NN, DHID, DIN);

    // L2-4: GEMM (fp32 out) -> hF ; slice-agg (8 XCD-pinned slices) -> Y
    k_mgemm<0><<<dim3(4, gy), 256, 0, stream>>>(Yh, Yl, w2h, w2l, nullptr, nullptr, nullptr, hF,
                                                NN, DHID, DHID);
    k_aggs<DHID, 8, 2><<<NN * 8, 64, 0, stream>>>(hF, dinv, rp, es, ewn, b2, nullptr, Yh, Yl);
    k_mgemm<0><<<dim3(4, gy), 256, 0, stream>>>(Yh, Yl, w3h, w3l, nullptr, nullptr, nullptr, hF,
                                                NN, DHID, DHID);
    k_aggs<DHID, 8, 2><<<NN * 8, 64, 0, stream>>>(hF, dinv, rp, es, ewn, b3, nullptr, Yh, Yl);
    k_mgemm<0><<<dim3(4, gy), 256, 0, stream>>>(Yh, Yl, w4h, w4l, nullptr, nullptr, nullptr, hF,
                                                NN, DHID, DHID);
    k_aggs<DHID, 8, 2><<<NN * 8, 64, 0, stream>>>(hF, dinv, rp, es, ewn, b4, nullptr, Yh, Yl);

    // L5: GEMM (512->128, fp32 out) -> hF ; agg (2 slices, +b5+relu, fp32) -> hOut
    k_mgemm<0><<<dim3(1, gy), 256, 0, stream>>>(Yh, Yl, w5h, w5l, nullptr, nullptr, nullptr, hF,
                                                NN, DOUT, DHID);
    k_aggs<DOUT, 2, 0><<<NN * 2, 64, 0, stream>>>(hF, dinv, rp, es, ewn, b5, hOut,
                                                  nullptr, nullptr);

    // Mean pool: two-stage deterministic partition reduce
    k_pool_part<<<dim3(NG, POOL_P), DOUT, 0, stream>>>(hOut, gstart, ppart);
    k_pool_fin<<<NG, DOUT, 0, stream>>>(ppart, gstart, (float*)d_out);
}

// Round 12
// 364.473 us; speedup vs baseline: 1.9387x; 1.0418x over previous
//
#include <hip/hip_runtime.h>
#include <stdint.h>

#define NN 10000
#define NE 150000
#define NG 64
#define DIN 128
#define DHID 512
#define DOUT 128
#define POOL_P 16  // pool partitions per graph
#define NRP8 80    // row panels (79) rounded to multiple of 8

typedef float f32x4 __attribute__((ext_vector_type(4)));
typedef short s16x8 __attribute__((ext_vector_type(8)));
typedef unsigned short us4 __attribute__((ext_vector_type(4)));
typedef unsigned short us2 __attribute__((ext_vector_type(2)));
typedef unsigned short ushort_t;

// ---------------------------------------------------------------------------
// bf16 helpers (RNE)
// ---------------------------------------------------------------------------
__device__ __forceinline__ ushort_t f2bf(float f) {
    unsigned u = __float_as_uint(f);
    u += 0x7FFFu + ((u >> 16) & 1u);
    return (ushort_t)(u >> 16);
}
__device__ __forceinline__ float bf2f(ushort_t s) {
    return __uint_as_float(((unsigned)s) << 16);
}

__device__ __forceinline__ void gl_lds16(const void* g, void* l) {
    __builtin_amdgcn_global_load_lds(
        (const __attribute__((address_space(1))) unsigned int*)g,
        (__attribute__((address_space(3))) unsigned int*)l, 16, 0, 0);
}

__device__ __forceinline__ void mfma_bf16(f32x4& d, s16x8 a, s16x8 b) {
    asm("v_mfma_f32_16x16x32_bf16 %0, %1, %2, %0" : "+v"(d) : "v"(a), "v"(b));
}

// ---------------------------------------------------------------------------
// CSR build
// ---------------------------------------------------------------------------
__global__ void k_edges_count(const int* __restrict__ dst, int* __restrict__ cnt, int E) {
    int e = blockIdx.x * blockDim.x + threadIdx.x;
    if (e < E) atomicAdd(&cnt[dst[e]], 1);
}

__global__ void k_dinv(const int* __restrict__ cnt, float* __restrict__ dinv, int n) {
    int i = blockIdx.x * blockDim.x + threadIdx.x;
    if (i < n) dinv[i] = rsqrtf(1.0f + (float)cnt[i]);  // +1 self loop
}

// 1024-thread single-block exclusive scan of cnt[0..NN) -> rp[0..NN]
__global__ void k_scan2(const int* __restrict__ cnt, int* __restrict__ rp) {
    const int C = 10;  // 1024*10 >= 10001
    const int t = threadIdx.x;
    const int lane = t & 63, w = t >> 6;
    const int base = t * C;
    int v[C];
    int s = 0;
#pragma unroll
    for (int j = 0; j < C; j++) {
        int i = base + j;
        v[j] = (i < NN) ? cnt[i] : 0;
        s += v[j];
    }
    int sc = s;
#pragma unroll
    for (int off = 1; off < 64; off <<= 1) {
        int tv = __shfl_up(sc, off);
        if (lane >= off) sc += tv;
    }
    __shared__ int wsum[16], woff[16];
    if (lane == 63) wsum[w] = sc;
    __syncthreads();
    if (t == 0) {
        int c = 0;
#pragma unroll
        for (int k = 0; k < 16; k++) { woff[k] = c; c += wsum[k]; }
    }
    __syncthreads();
    int pre = woff[w] + (sc - s);
#pragma unroll
    for (int j = 0; j < C; j++) {
        int i = base + j;
        if (i <= NN) rp[i] = pre;
        pre += v[j];
    }
}

__global__ void k_scatter(const int* __restrict__ src, const int* __restrict__ dst,
                          const float* __restrict__ dinv, const int* __restrict__ rp,
                          int* __restrict__ fill, int* __restrict__ es,
                          float* __restrict__ ew, int E) {
    int e = blockIdx.x * blockDim.x + threadIdx.x;
    if (e < E) {
        int d = dst[e], s = src[e];
        int p = rp[d] + atomicAdd(&fill[d], 1);
        es[p] = s;
        ew[p] = dinv[s] * dinv[d];
    }
}

// ---------------------------------------------------------------------------
// Weight transpose + bf16 hi/lo split (all 5 layers, one launch)
// ---------------------------------------------------------------------------
__global__ void k_split_w(const float* __restrict__ W1, const float* __restrict__ W2,
                          const float* __restrict__ W3, const float* __restrict__ W4,
                          const float* __restrict__ W5,
                          ushort_t* __restrict__ th, ushort_t* __restrict__ tl) {
    int t = blockIdx.x * blockDim.x + threadIdx.x;
    const float* W;
    int K, Mw, off, r;
    if (t < 65536)       { W = W1; K = 128; Mw = 512; off = 0;      r = t; }
    else if (t < 327680) { W = W2; K = 512; Mw = 512; off = 65536;  r = t - 65536; }
    else if (t < 589824) { W = W3; K = 512; Mw = 512; off = 327680; r = t - 327680; }
    else if (t < 851968) { W = W4; K = 512; Mw = 512; off = 589824; r = t - 589824; }
    else if (t < 917504) { W = W5; K = 512; Mw = 128; off = 851968; r = t - 851968; }
    else return;
    const int k = r / Mw, m = r % Mw;
    const float f = W[r];
    const ushort_t h = f2bf(f);
    const ushort_t l = f2bf(f - bf2f(h));
    const int o = off + m * K + k;
    th[o] = h;
    tl[o] = l;
}

// ---------------------------------------------------------------------------
// bf16x3 split MFMA GEMM: C[M][N] = (Ah+Al)[M][K] @ (Bh+Bl)^T  (Bt is [N][K])
// 128x128 tile, BK=32, 4 waves (2x2 of 64x64), 16x16x32 MFMA, LDS dbuf.
// XCD-grouped flat grid: all (1<<NCSHIFT) col-tiles of a row-panel share
// wg%8 -> same XCD -> A-panel (256KB pair) fetched once into that XCD's L2
// (per-XCD A working set: 10 panels x 256KB = 2.56MB < 4MB).
// EPI: 0 = fp32 C out; 2 = bias+relu+split-pair out.
// ---------------------------------------------------------------------------
template <int EPI, int NCSHIFT>
__global__ __launch_bounds__(256, 2) void k_mgemm(
    const ushort_t* __restrict__ Ah, const ushort_t* __restrict__ Al,
    const ushort_t* __restrict__ Bh, const ushort_t* __restrict__ Bl,
    const float* __restrict__ bias,
    ushort_t* __restrict__ Ch, ushort_t* __restrict__ Cl, float* __restrict__ Cf,
    const int M, const int N, const int K) {
    __shared__ ushort_t sAh[2][128 * 32], sAl[2][128 * 32];
    __shared__ ushort_t sBh[2][128 * 32], sBl[2][128 * 32];
    const int wg = blockIdx.x;
    const int rpan = ((wg >> (3 + NCSHIFT)) << 3) | (wg & 7);
    const int cc = (wg >> 3) & ((1 << NCSHIFT) - 1);
    const int row0 = rpan * 128, col0 = cc * 128;
    if (row0 >= M) return;  // block-uniform exit (padded panel)

    const int tid = threadIdx.x;
    const int lane = tid & 63, wv = tid >> 6;
    const int ln = lane & 15, lhi = lane >> 4;
    const int kg = lhi * 8;
    const int wr = (wv >> 1) * 64, wc = (wv & 1) * 64;
    const int sr = tid >> 2;
    const int sk = (tid & 3) * 8;

    auto STAGE = [&](int buf, int k0) {
        const int koff = k0 + sk;
        int ra0 = row0 + sr;      if (ra0 > M - 1) ra0 = M - 1;
        int ra1 = row0 + 64 + sr; if (ra1 > M - 1) ra1 = M - 1;
        gl_lds16(&Ah[(size_t)ra0 * K + koff], &sAh[buf][sr * 32 + sk]);
        gl_lds16(&Ah[(size_t)ra1 * K + koff], &sAh[buf][(64 + sr) * 32 + sk]);
        gl_lds16(&Al[(size_t)ra0 * K + koff], &sAl[buf][sr * 32 + sk]);
        gl_lds16(&Al[(size_t)ra1 * K + koff], &sAl[buf][(64 + sr) * 32 + sk]);
        const size_t cb0 = (size_t)(col0 + sr) * K + koff;
        const size_t cb1 = (size_t)(col0 + 64 + sr) * K + koff;
        gl_lds16(&Bh[cb0], &sBh[buf][sr * 32 + sk]);
        gl_lds16(&Bh[cb1], &sBh[buf][(64 + sr) * 32 + sk]);
        gl_lds16(&Bl[cb0], &sBl[buf][sr * 32 + sk]);
        gl_lds16(&Bl[cb1], &sBl[buf][(64 + sr) * 32 + sk]);
    };

    f32x4 acc[4][4] = {};

    STAGE(0, 0);
    __syncthreads();  // drain prologue staging

    const int nk = K / 32;
    for (int t = 0; t < nk; t++) {
        const int cur = t & 1;
        if (t + 1 < nk) STAGE(cur ^ 1, (t + 1) * 32);  // async prefetch

        s16x8 a_h[4], a_l[4], b_h[4], b_l[4];
#pragma unroll
        for (int m = 0; m < 4; m++) {
            const int r = (wr + m * 16 + ln) * 32 + kg;
            a_h[m] = *reinterpret_cast<const s16x8*>(&sAh[cur][r]);
            a_l[m] = *reinterpret_cast<const s16x8*>(&sAl[cur][r]);
        }
#pragma unroll
        for (int n = 0; n < 4; n++) {
            const int c = (wc + n * 16 + ln) * 32 + kg;
            b_h[n] = *reinterpret_cast<const s16x8*>(&sBh[cur][c]);
            b_l[n] = *reinterpret_cast<const s16x8*>(&sBl[cur][c]);
        }
#pragma unroll
        for (int m = 0; m < 4; m++)
#pragma unroll
            for (int n = 0; n < 4; n++) {
                mfma_bf16(acc[m][n], a_h[m], b_h[n]);
                mfma_bf16(acc[m][n], a_h[m], b_l[n]);
                mfma_bf16(acc[m][n], a_l[m], b_h[n]);
            }
        __syncthreads();  // drains prefetch vmcnt + this iter's lgkm
    }

    asm volatile("s_nop 7\n\ts_nop 7");  // MFMA->VALU hazard guard

#pragma unroll
    for (int n = 0; n < 4; n++) {
        const int col = col0 + wc + n * 16 + ln;
        const float bv = (EPI == 2) ? bias[col] : 0.0f;
#pragma unroll
        for (int m = 0; m < 4; m++) {
#pragma unroll
            for (int j = 0; j < 4; j++) {
                const int row = row0 + wr + m * 16 + lhi * 4 + j;
                if (row < M) {
                    float f = acc[m][n][j];
                    const size_t o = (size_t)row * N + col;
                    if constexpr (EPI == 2) {
                        f = fmaxf(f + bv, 0.0f);
                        const ushort_t h = f2bf(f);
                        Ch[o] = h;
                        Cl[o] = f2bf(f - bf2f(h));
                    } else {
                        Cf[o] = f;
                    }
                }
            }
        }
    }
}

// ---------------------------------------------------------------------------
// Slice-aggregation: feature dim split into NSLICE slices of 64 cols.
// slice = bid & (NSLICE-1): with NSLICE==8 each slice pins to one XCD, so the
// slice's gather working set (NN*64*4B = 2.56MB) stays in that XCD's 4MB L2.
// OUTM: 0 = fp32 out +bias+relu; 1 = split-pair plain; 2 = split +bias+relu.
// ---------------------------------------------------------------------------
template <int M_, int NSLICE, int OUTM>
__global__ void k_aggs(const float* __restrict__ xf, const float* __restrict__ dinv,
                       const int* __restrict__ rp, const int* __restrict__ es,
                       const float* __restrict__ ew, const float* __restrict__ bias,
                       float* __restrict__ of, ushort_t* __restrict__ oh,
                       ushort_t* __restrict__ ol) {
    constexpr int SHIFT = (NSLICE == 8) ? 3 : 1;
    const int bid = blockIdx.x;
    const int slice = bid & (NSLICE - 1);
    const int node = bid >> SHIFT;
    const int f = threadIdx.x;  // 0..63
    const int col = slice * 64 + f;
    const size_t base = (size_t)node * M_ + col;

    __shared__ int s_src[64];
    __shared__ float s_w[64];

    const float di = dinv[node];
    const float sw = di * di;
    float a0 = xf[base] * sw, a1 = 0.f, a2 = 0.f, a3 = 0.f;

    const int beg = rp[node], end = rp[node + 1];
    for (int c = beg; c < end; c += 64) {
        const int m = min(64, end - c);
        __syncthreads();
        if (f < m) { s_src[f] = es[c + f]; s_w[f] = ew[c + f]; }
        __syncthreads();
        int e = 0;
        for (; e + 3 < m; e += 4) {
            const float w0 = s_w[e], w1 = s_w[e + 1], w2 = s_w[e + 2], w3 = s_w[e + 3];
            const float v0 = xf[(size_t)s_src[e] * M_ + col];
            const float v1 = xf[(size_t)s_src[e + 1] * M_ + col];
            const float v2 = xf[(size_t)s_src[e + 2] * M_ + col];
            const float v3 = xf[(size_t)s_src[e + 3] * M_ + col];
            a0 = fmaf(v0, w0, a0); a1 = fmaf(v1, w1, a1);
            a2 = fmaf(v2, w2, a2); a3 = fmaf(v3, w3, a3);
        }
        for (; e < m; e++) a0 = fmaf(xf[(size_t)s_src[e] * M_ + col], s_w[e], a0);
    }

    float v = (a0 + a1) + (a2 + a3);
    if constexpr (OUTM != 1) v = fmaxf(v + bias[col], 0.0f);
    if constexpr (OUTM == 0) {
        of[base] = v;
    } else {
        const ushort_t h = f2bf(v);
        oh[base] = h;
        ol[base] = f2bf(v - bf2f(h));
    }
}

// ---------------------------------------------------------------------------
// Mean pool: batch is SORTED -> per-graph contiguous ranges, no atomics.
// Two-stage partition reduce for occupancy.
// ---------------------------------------------------------------------------
__global__ void k_gbounds(const int* __restrict__ batch, int* __restrict__ gstart) {
    const int g = threadIdx.x;  // 0..64
    if (g > NG) return;
    int lo = 0, hi = NN;  // first index with batch[i] >= g
    while (lo < hi) {
        int mid = (lo + hi) >> 1;
        if (batch[mid] < g) lo = mid + 1; else hi = mid;
    }
    gstart[g] = lo;
}

// Stage A: grid (NG, POOL_P), 128 thr. partial[(g*POOL_P+p)*DOUT + f]
__global__ void k_pool_part(const float* __restrict__ h, const int* __restrict__ gstart,
                            float* __restrict__ partial) {
    const int g = blockIdx.x, p = blockIdx.y;
    const int f = threadIdx.x;  // 128
    const int s = gstart[g], e = gstart[g + 1];
    const int len = e - s;
    const int chunk = (len + POOL_P - 1) / POOL_P;
    const int i0 = s + p * chunk;
    const int i1 = min(i0 + chunk, e);
    float a0 = 0.f, a1 = 0.f, a2 = 0.f, a3 = 0.f;
    int i = i0;
    for (; i + 3 < i1; i += 4) {
        a0 += h[(size_t)(i + 0) * DOUT + f];
        a1 += h[(size_t)(i + 1) * DOUT + f];
        a2 += h[(size_t)(i + 2) * DOUT + f];
        a3 += h[(size_t)(i + 3) * DOUT + f];
    }
    for (; i < i1; i++) a0 += h[(size_t)i * DOUT + f];
    partial[(size_t)(g * POOL_P + p) * DOUT + f] = (a0 + a1) + (a2 + a3);
}

// Stage B: grid NG, 128 thr: reduce POOL_P partials, divide by count.
__global__ void k_pool_fin(const float* __restrict__ partial, const int* __restrict__ gstart,
                           float* __restrict__ out) {
    const int g = blockIdx.x;
    const int f = threadIdx.x;
    float acc = 0.f;
#pragma unroll
    for (int p = 0; p < POOL_P; p++) acc += partial[(size_t)(g * POOL_P + p) * DOUT + f];
    const float cnt = (float)(gstart[g + 1] - gstart[g]);
    out[(size_t)g * DOUT + f] = acc / fmaxf(cnt, 1.0f);
}

// ---------------------------------------------------------------------------
extern "C" void kernel_launch(void* const* d_in, const int* in_sizes, int n_in,
                              void* d_out, int out_size, void* d_ws, size_t ws_size,
                              hipStream_t stream) {
    const float* x = (const float*)d_in[0];
    const int* ei = (const int*)d_in[1];
    const int* batch = (const int*)d_in[2];
    const float* b1 = (const float*)d_in[4];
    const float* b2 = (const float*)d_in[6];
    const float* b3 = (const float*)d_in[8];
    const float* b4 = (const float*)d_in[10];
    const float* b5 = (const float*)d_in[12];
    const int* src = ei;
    const int* dst = ei + NE;

    char* ws = (char*)d_ws;
    size_t off = 0;
    auto alloc = [&](size_t bytes) -> char* {
        char* p = ws + off;
        off = (off + bytes + 255) & ~(size_t)255;
        return p;
    };
    float* dinv = (float*)alloc(NN * 4);
    int* cnt    = (int*)alloc(NN * 4);
    int* rp     = (int*)alloc((NN + 1) * 4);
    int* fill   = (int*)alloc(NN * 4);
    int* es     = (int*)alloc(NE * 4);
    float* ewn  = (float*)alloc(NE * 4);
    int* gstart = (int*)alloc((NG + 1) * 4);
    float* ppart = (float*)alloc((size_t)NG * POOL_P * DOUT * 4);
    ushort_t* wth = (ushort_t*)alloc(917504 * 2);
    ushort_t* wtl = (ushort_t*)alloc(917504 * 2);
    ushort_t* Xh = (ushort_t*)alloc((size_t)NN * DHID * 2);
    ushort_t* Xl = (ushort_t*)alloc((size_t)NN * DHID * 2);
    ushort_t* Yh = (ushort_t*)alloc((size_t)NN * DHID * 2);
    ushort_t* Yl = (ushort_t*)alloc((size_t)NN * DHID * 2);
    float* hF = (float*)alloc((size_t)NN * DHID * 4);  // fp32 GEMM out
    float* hOut = (float*)Xh;  // fp32 final activations (X dead by L5)
    (void)ws_size; (void)n_in; (void)in_sizes;

    hipMemsetAsync(cnt, 0, NN * 4, stream);
    hipMemsetAsync(fill, 0, NN * 4, stream);

    // CSR + norm build
    k_edges_count<<<(NE + 255) / 256, 256, 0, stream>>>(dst, cnt, NE);
    k_dinv<<<(NN + 255) / 256, 256, 0, stream>>>(cnt, dinv, NN);
    k_scan2<<<1, 1024, 0, stream>>>(cnt, rp);
    k_scatter<<<(NE + 255) / 256, 256, 0, stream>>>(src, dst, dinv, rp, fill, es, ewn, NE);
    k_gbounds<<<1, 128, 0, stream>>>(batch, gstart);

    // Weight transpose+split
    k_split_w<<<(917504 + 255) / 256, 256, 0, stream>>>(
        (const float*)d_in[3], (const float*)d_in[5], (const float*)d_in[7],
        (const float*)d_in[9], (const float*)d_in[11], wth, wtl);

    const ushort_t *w1h = wth, *w1l = wtl;
    const ushort_t *w2h = wth + 65536, *w2l = wtl + 65536;
    const ushort_t *w3h = wth + 327680, *w3l = wtl + 327680;
    const ushort_t *w4h = wth + 589824, *w4l = wtl + 589824;
    const ushort_t *w5h = wth + 851968, *w5l = wtl + 851968;

    // L1: agg(x, 128-dim, 2 slices) -> pair X ; GEMM1(+b1+relu) -> pair Y
    k_aggs<DIN, 2, 1><<<NN * 2, 64, 0, stream>>>(x, dinv, rp, es, ewn, nullptr,
                                                 nullptr, Xh, Xl);
    k_mgemm<2, 2><<<NRP8 * 4, 256, 0, stream>>>(Xh, Xl, w1h, w1l, b1, Yh, Yl, nullptr,
                                                NN, DHID, DIN);

    // L2-4: GEMM (fp32 out, XCD-grouped) -> hF ; slice-agg (8 XCD slices) -> Y
    k_mgemm<0, 2><<<NRP8 * 4, 256, 0, stream>>>(Yh, Yl, w2h, w2l, nullptr, nullptr, nullptr, hF,
                                                NN, DHID, DHID);
    k_aggs<DHID, 8, 2><<<NN * 8, 64, 0, stream>>>(hF, dinv, rp, es, ewn, b2, nullptr, Yh, Yl);
    k_mgemm<0, 2><<<NRP8 * 4, 256, 0, stream>>>(Yh, Yl, w3h, w3l, nullptr, nullptr, nullptr, hF,
                                                NN, DHID, DHID);
    k_aggs<DHID, 8, 2><<<NN * 8, 64, 0, stream>>>(hF, dinv, rp, es, ewn, b3, nullptr, Yh, Yl);
    k_mgemm<0, 2><<<NRP8 * 4, 256, 0, stream>>>(Yh, Yl, w4h, w4l, nullptr, nullptr, nullptr, hF,
                                                NN, DHID, DHID);
    k_aggs<DHID, 8, 2><<<NN * 8, 64, 0, stream>>>(hF, dinv, rp, es, ewn, b4, nullptr, Yh, Yl);

    // L5: GEMM (512->128, fp32 out) -> hF ; agg (2 slices, +b5+relu, fp32) -> hOut
    k_mgemm<0, 0><<<NRP8, 256, 0, stream>>>(Yh, Yl, w5h, w5l, nullptr, nullptr, nullptr, hF,
                                            NN, DOUT, DHID);
    k_aggs<DOUT, 2, 0><<<NN * 2, 64, 0, stream>>>(hF, dinv, rp, es, ewn, b5, hOut,
                                                  nullptr, nullptr);

    // Mean pool: two-stage deterministic partition reduce
    k_pool_part<<<dim3(NG, POOL_P), DOUT, 0, stream>>>(hOut, gstart, ppart);
    k_pool_fin<<<NG, DOUT, 0, stream>>>(ppart, gstart, (float*)d_out);
}